// Round 1
// baseline (128.200 us; speedup 1.0000x reference)
//
#include <hip/hip_runtime.h>
#include <math.h>

typedef unsigned short u16;
typedef unsigned int u32;
typedef __bf16 bf16x8 __attribute__((ext_vector_type(8)));
typedef float f32x4 __attribute__((ext_vector_type(4)));

__device__ __forceinline__ u16 f2b(float f) {
  u32 u = __builtin_bit_cast(u32, f);
  u32 r = (u + 0x7FFFu + ((u >> 16) & 1u)) >> 16;
  return (u16)r;
}

__device__ __forceinline__ void glds16(const void* g, void* lds) {
  __builtin_amdgcn_global_load_lds(
      (const __attribute__((address_space(1))) void*)(void*)(const_cast<void*>(g)),
      (__attribute__((address_space(3))) void*)lds, 16, 0, 0);
}

// ---------------- prep kernels ----------------

// x [8192][512] fp32 -> bf16
__global__ __launch_bounds__(256) void castx(const float* __restrict__ x, u16* __restrict__ xb) {
  int idx = blockIdx.x * 256 + threadIdx.x;  // 4096*256 = 1,048,576 float4s
  float4 v = ((const float4*)x)[idx];
  ushort4 o;
  o.x = f2b(v.x); o.y = f2b(v.y); o.z = f2b(v.z); o.w = f2b(v.w);
  ((ushort4*)xb)[idx] = o;
}

// WbigT rows: [0,512)=Wq^T*scale, [512,1024)=Wk^T, [1024,1536)=Wv^T,
// rows [2040,2048)=0.  WoT = Wo^T.  (rows [1536,2040) come from wpe_kernel)
__global__ __launch_bounds__(256) void buildw(const float* __restrict__ Wq, const float* __restrict__ Wk,
                                              const float* __restrict__ Wv, const float* __restrict__ Wo,
                                              u16* __restrict__ WbigT, u16* __restrict__ WoT) {
  const float SCALE = 0.08838834764831845f;  // 1/sqrt(128)
  int row = blockIdx.x;  // 0..2055
  int t = threadIdx.x;
  if (row < 512) {
    for (int k = t; k < 512; k += 256) WbigT[row*512 + k] = f2b(Wq[k*512 + row] * SCALE);
  } else if (row < 1024) {
    int n = row - 512;
    for (int k = t; k < 512; k += 256) WbigT[row*512 + k] = f2b(Wk[k*512 + n]);
  } else if (row < 1536) {
    int n = row - 1024;
    for (int k = t; k < 512; k += 256) WbigT[row*512 + k] = f2b(Wv[k*512 + n]);
  } else if (row < 1544) {
    int rr = row - 1536 + 2040;
    for (int k = t; k < 512; k += 256) WbigT[rr*512 + k] = 0;
  } else {
    int n = row - 1544;
    for (int k = t; k < 512; k += 256) WoT[n*512 + k] = f2b(Wo[k*512 + n]);
  }
}

// WbigT rows [1536,1788): (Wq @ pe_w * scale)^T per head; [1788,2040): pe_h.
// row = 1536 + h*63 + r  holds column vector over k of  scale * sum_d Wq[k][h*128+d]*pe_w[d][r]
__global__ __launch_bounds__(256) void wpe_kernel(const float* __restrict__ Wq, const float* __restrict__ pew,
                                                  const float* __restrict__ peh, u16* __restrict__ WbigT) {
  int k = blockIdx.x;  // 0..511
  int t = threadIdx.x;
  __shared__ float wrow[512];
  for (int j = t; j < 512; j += 256) wrow[j] = Wq[k*512 + j];
  __syncthreads();
  if (t < 252) {
    int h = t / 63, r = t - h*63;
    float aw = 0.f, ah = 0.f;
    for (int d = 0; d < 128; d++) {
      float qv = wrow[h*128 + d];
      aw += qv * pew[d*63 + r];
      ah += qv * peh[d*63 + r];
    }
    const float SCALE = 0.08838834764831845f;
    WbigT[(size_t)(1536 + t)*512 + k] = f2b(aw * SCALE);
    WbigT[(size_t)(1788 + t)*512 + k] = f2b(ah * SCALE);
  }
}

// ---------------- GEMM (A row-major [M][512] bf16, Bt = B^T [N][512] bf16) ----------------
// 128x128 tile, 4 waves (2x2), 16x16x32 bf16 MFMA, global_load_lds w/ pre-swizzled source.
// MODE 0: plain fp32 out [M][512].  MODE 1: QKV+REL routing epilogue (N=2048).
template<int MODE>
__global__ __launch_bounds__(256) void gemm_bt(
    const u16* __restrict__ A, const u16* __restrict__ Bt,
    float* __restrict__ outF,
    u16* __restrict__ Qb, u16* __restrict__ Kb, u16* __restrict__ Vt,
    float* __restrict__ RELW, float* __restrict__ RELH)
{
  __shared__ u16 As[128*64];
  __shared__ u16 Bs[128*64];
  const int tid = threadIdx.x;
  const int w = tid >> 6, l = tid & 63, g = l >> 4, c = l & 15;
  const int bm = blockIdx.x, bn = blockIdx.y;
  const int wm = (w >> 1) * 64, wn = (w & 1) * 64;

  f32x4 acc[4][4];
#pragma unroll
  for (int i = 0; i < 4; i++)
#pragma unroll
    for (int j = 0; j < 4; j++) acc[i][j] = f32x4{0.f, 0.f, 0.f, 0.f};

  const char* Ab = (const char*)A;
  const char* Bb = (const char*)Bt;
  const int rsub = l >> 3;                         // row within 8-row chunk
  const int csw = (((l & 7) ^ rsub) << 4);         // pre-swizzled source byte within 128B row-slice

  for (int kb = 0; kb < 8; kb++) {
    __syncthreads();
    const int kbyte = kb * 128;
#pragma unroll
    for (int t = 0; t < 4; t++) {
      const int row = (w*4 + t)*8 + rsub;
      glds16(Ab + (size_t)(bm*128 + row) * 1024 + kbyte + csw, (char*)As + (w*4 + t)*1024);
      glds16(Bb + (size_t)(bn*128 + row) * 1024 + kbyte + csw, (char*)Bs + (w*4 + t)*1024);
    }
    asm volatile("s_waitcnt vmcnt(0)" ::: "memory");
    __syncthreads();
#pragma unroll
    for (int ks = 0; ks < 2; ks++) {
      const int koff = (ks*64 + g*16) ^ ((c & 7) << 4);
      bf16x8 af[4], bfr[4];
#pragma unroll
      for (int mf = 0; mf < 4; mf++)
        af[mf] = *(const bf16x8*)((const char*)As + (wm + mf*16 + c)*128 + koff);
#pragma unroll
      for (int nf = 0; nf < 4; nf++)
        bfr[nf] = *(const bf16x8*)((const char*)Bs + (wn + nf*16 + c)*128 + koff);
#pragma unroll
      for (int mf = 0; mf < 4; mf++)
#pragma unroll
        for (int nf = 0; nf < 4; nf++)
          acc[mf][nf] = __builtin_amdgcn_mfma_f32_16x16x32_bf16(af[mf], bfr[nf], acc[mf][nf], 0, 0, 0);
    }
  }

  if (MODE == 0) {
#pragma unroll
    for (int mf = 0; mf < 4; mf++) {
#pragma unroll
      for (int nf = 0; nf < 4; nf++) {
        const int n = bn*128 + wn + nf*16 + c;
#pragma unroll
        for (int r = 0; r < 4; r++) {
          const int m = bm*128 + wm + mf*16 + g*4 + r;
          outF[(size_t)m*512 + n] = acc[mf][nf][r];
        }
      }
    }
  } else {
#pragma unroll
    for (int mf = 0; mf < 4; mf++) {
#pragma unroll
      for (int nf = 0; nf < 4; nf++) {
        const int n = bn*128 + wn + nf*16 + c;
#pragma unroll
        for (int r = 0; r < 4; r++) {
          const int m = bm*128 + wm + mf*16 + g*4 + r;   // = b*1024 + i
          const int b = m >> 10, i = m & 1023;
          const float v = acc[mf][nf][r];
          if (n < 512) {
            int h = n >> 7, d = n & 127;
            Qb[(size_t)((b*4 + h)*1024 + i)*128 + d] = f2b(v);
          } else if (n < 1024) {
            int h = (n - 512) >> 7, d = n & 127;
            Kb[(size_t)((b*4 + h)*1024 + i)*128 + d] = f2b(v);
          } else if (n < 1536) {
            int h = (n - 1024) >> 7, d = n & 127;
            Vt[(size_t)((b*4 + h)*128 + d)*1024 + i] = f2b(v);
          } else if (n < 1788) {
            int q = n - 1536, h = q / 63, r2 = q - h*63;
            RELW[(size_t)((b*4 + h)*1024 + i)*64 + r2] = v;
          } else if (n < 2040) {
            int q = n - 1788, h = q / 63, r2 = q - h*63;
            RELH[(size_t)((b*4 + h)*1024 + i)*64 + r2] = v;
          }
        }
      }
    }
  }
}

// ---------------- fused flash attention with decomposed relative bias ----------------
// grid (32 bh, 16 q-tiles), 256 threads (4 waves x 16 Q-rows). K/V tiles of 128 in LDS.
__global__ __launch_bounds__(256) void attn_fused(
    const u16* __restrict__ Qb, const u16* __restrict__ Kb, const u16* __restrict__ Vt,
    const float* __restrict__ RELW, const float* __restrict__ RELH,
    u16* __restrict__ AO)
{
  __shared__ u16 Kt[128*128];     // [j][d] swizzled
  __shared__ u16 Vts[128*128];    // [d][j] swizzled
  __shared__ u16 Pl[4*16*128];    // per-wave P [16][128] swizzled
  const int tid = threadIdx.x;
  const int w = tid >> 6, l = tid & 63, g = l >> 4, c = l & 15;
  const int bh = blockIdx.x, qt = blockIdx.y;
  const int i0 = qt * 64;

  // Q fragments for this wave's 16 rows: A-frag row = c, k = s*32 + g*8 + [0,8)
  bf16x8 qf[4];
  {
    const char* qbase = (const char*)Qb + (size_t)(bh*1024 + i0 + w*16 + c) * 256;
#pragma unroll
    for (int s = 0; s < 4; s++) qf[s] = *(const bf16x8*)(qbase + s*64 + g*16);
  }

  f32x4 Oacc[8];
#pragma unroll
  for (int fd = 0; fd < 8; fd++) Oacc[fd] = f32x4{0.f, 0.f, 0.f, 0.f};
  float mrow[4] = {-INFINITY, -INFINITY, -INFINITY, -INFINITY};
  float lrow[4] = {0.f, 0.f, 0.f, 0.f};

  for (int jt = 0; jt < 8; jt++) {
    const int j0 = jt * 128;
    __syncthreads();
#pragma unroll
    for (int t = 0; t < 8; t++) {
      const int o = (w*8 + t)*1024 + l*16;
      const int row = o >> 8;
      const int csw2 = (o & 255) ^ ((row & 7) << 4);
      glds16((const char*)Kb + (size_t)(bh*1024 + j0 + row) * 256 + csw2, (char*)Kt + (w*8 + t)*1024);
      glds16((const char*)Vt + (size_t)(bh*128 + row) * 2048 + j0*2 + csw2, (char*)Vts + (w*8 + t)*1024);
    }
    asm volatile("s_waitcnt vmcnt(0)" ::: "memory");
    __syncthreads();

    // S = Q K^T for this tile: acc[fn] covers cols fn*16..+16
    f32x4 acc[8];
#pragma unroll
    for (int fn = 0; fn < 8; fn++) acc[fn] = f32x4{0.f, 0.f, 0.f, 0.f};
#pragma unroll
    for (int s = 0; s < 4; s++) {
      const int koff = (s*64 + g*16) ^ ((c & 7) << 4);
#pragma unroll
      for (int fn = 0; fn < 8; fn++) {
        bf16x8 kf = *(const bf16x8*)((const char*)Kt + (fn*16 + c)*256 + koff);
        acc[fn] = __builtin_amdgcn_mfma_f32_16x16x32_bf16(qf[s], kf, acc[fn], 0, 0, 0);
      }
    }

    // bias + online softmax (C-frag: row = g*4+r, col = fn*16+c)
#pragma unroll
    for (int r = 0; r < 4; r++) {
      const int i = i0 + w*16 + g*4 + r;
      const int xi = i & 31, yi = i >> 5;
      const float* rw = RELW + ((size_t)(bh*1024 + i) << 6);
      const float* rh = RELH + ((size_t)(bh*1024 + i) << 6);
      const float xw0 = rw[c - xi + 31];        // x2 = c        (fn even)
      const float xw1 = rw[c + 16 - xi + 31];   // x2 = c + 16   (fn odd)
      float yhv[4];
#pragma unroll
      for (int fh = 0; fh < 4; fh++) yhv[fh] = rh[jt*4 + fh - yi + 31];
      float mx = -INFINITY;
#pragma unroll
      for (int fn = 0; fn < 8; fn++) {
        float sb = acc[fn][r] + ((fn & 1) ? xw1 : xw0) + yhv[fn >> 1];
        acc[fn][r] = sb;
        mx = fmaxf(mx, sb);
      }
      mx = fmaxf(mx, __shfl_xor(mx, 1));
      mx = fmaxf(mx, __shfl_xor(mx, 2));
      mx = fmaxf(mx, __shfl_xor(mx, 4));
      mx = fmaxf(mx, __shfl_xor(mx, 8));
      const float mnew = fmaxf(mrow[r], mx);
      const float sc = __expf(mrow[r] - mnew);
      mrow[r] = mnew;
      float ps = 0.f;
      const int rowl = g*4 + r;
      char* pb = (char*)Pl + w*4096 + rowl*256;
      const int swz = (rowl & 7) << 4;
#pragma unroll
      for (int fn = 0; fn < 8; fn++) {
        float p = __expf(acc[fn][r] - mnew);
        ps += p;
        *(u16*)(pb + (((fn*16 + c)*2) ^ swz)) = f2b(p);
      }
      ps += __shfl_xor(ps, 1);
      ps += __shfl_xor(ps, 2);
      ps += __shfl_xor(ps, 4);
      ps += __shfl_xor(ps, 8);
      lrow[r] = lrow[r] * sc + ps;
#pragma unroll
      for (int fd = 0; fd < 8; fd++) Oacc[fd][r] *= sc;
    }

    // O += P V   (A-frag of P: row = c, k(=j) = s*32 + g*8)
#pragma unroll
    for (int s = 0; s < 4; s++) {
      const int koff = (s*64 + g*16) ^ ((c & 7) << 4);
      bf16x8 pf = *(const bf16x8*)((const char*)Pl + w*4096 + c*256 + koff);
#pragma unroll
      for (int fd = 0; fd < 8; fd++) {
        bf16x8 vf = *(const bf16x8*)((const char*)Vts + (fd*16 + c)*256 + koff);
        Oacc[fd] = __builtin_amdgcn_mfma_f32_16x16x32_bf16(pf, vf, Oacc[fd], 0, 0, 0);
      }
    }
  }

  const int b = bh >> 2, h = bh & 3;
#pragma unroll
  for (int fd = 0; fd < 8; fd++) {
#pragma unroll
    for (int r = 0; r < 4; r++) {
      const int i = i0 + w*16 + g*4 + r;
      AO[(size_t)(b*1024 + i)*512 + h*128 + fd*16 + c] = f2b(Oacc[fd][r] / lrow[r]);
    }
  }
}

// ---------------- launcher ----------------
extern "C" void kernel_launch(void* const* d_in, const int* in_sizes, int n_in,
                              void* d_out, int out_size, void* d_ws, size_t ws_size,
                              hipStream_t stream) {
  const float* x   = (const float*)d_in[0];
  const float* Wq  = (const float*)d_in[1];
  const float* Wk  = (const float*)d_in[2];
  const float* Wv  = (const float*)d_in[3];
  const float* Wo  = (const float*)d_in[4];
  const float* pew = (const float*)d_in[5];
  const float* peh = (const float*)d_in[6];

  char* ws = (char*)d_ws;
  u16* xb    = (u16*)ws;    ws += (size_t)8192*512*2;      // 8.39 MB
  u16* WbigT = (u16*)ws;    ws += (size_t)2048*512*2;      // 2.10 MB
  u16* WoT   = (u16*)ws;    ws += (size_t)512*512*2;       // 0.52 MB
  u16* Qb    = (u16*)ws;    ws += (size_t)32*1024*128*2;   // 8.39 MB
  u16* Kb    = (u16*)ws;    ws += (size_t)32*1024*128*2;   // 8.39 MB
  u16* Vt    = (u16*)ws;    ws += (size_t)32*1024*128*2;   // 8.39 MB
  float* RELW = (float*)ws; ws += (size_t)32*1024*64*4;    // 8.39 MB
  float* RELH = (float*)ws; ws += (size_t)32*1024*64*4;    // 8.39 MB
  u16* AO    = (u16*)ws;    ws += (size_t)8192*512*2;      // 8.39 MB  (total ~61.9 MB)

  castx<<<4096, 256, 0, stream>>>(x, xb);
  buildw<<<2056, 256, 0, stream>>>(Wq, Wk, Wv, Wo, WbigT, WoT);
  wpe_kernel<<<512, 256, 0, stream>>>(Wq, pew, peh, WbigT);
  gemm_bt<1><<<dim3(64, 16), 256, 0, stream>>>(xb, WbigT, nullptr, Qb, Kb, Vt, RELW, RELH);
  attn_fused<<<dim3(32, 16), 256, 0, stream>>>(Qb, Kb, Vt, RELW, RELH, AO);
  gemm_bt<0><<<dim3(64, 4), 256, 0, stream>>>(AO, WoT, (float*)d_out,
                                              nullptr, nullptr, nullptr, nullptr, nullptr);
}

// Round 2
// 126.559 us; speedup vs baseline: 1.0130x; 1.0130x over previous
//
#include <hip/hip_runtime.h>
#include <math.h>

typedef unsigned short u16;
typedef unsigned int u32;
typedef __bf16 bf16x8 __attribute__((ext_vector_type(8)));
typedef float f32x4 __attribute__((ext_vector_type(4)));

__device__ __forceinline__ u16 f2b(float f) {
  u32 u = __builtin_bit_cast(u32, f);
  u32 r = (u + 0x7FFFu + ((u >> 16) & 1u)) >> 16;
  return (u16)r;
}

__device__ __forceinline__ void glds16(const void* g, void* lds) {
  __builtin_amdgcn_global_load_lds(
      (const __attribute__((address_space(1))) void*)(void*)(const_cast<void*>(g)),
      (__attribute__((address_space(3))) void*)lds, 16, 0, 0);
}

// ---------------- prep kernels ----------------

// x [8192][512] fp32 -> bf16
__global__ __launch_bounds__(256) void castx(const float* __restrict__ x, u16* __restrict__ xb) {
  int idx = blockIdx.x * 256 + threadIdx.x;
  float4 v = ((const float4*)x)[idx];
  ushort4 o;
  o.x = f2b(v.x); o.y = f2b(v.y); o.z = f2b(v.z); o.w = f2b(v.w);
  ((ushort4*)xb)[idx] = o;
}

// WbigT rows: [0,512)=Wq^T*scale, [512,1024)=Wk^T, [1024,1536)=Wv^T,
// rows [2040,2048)=0.  WoT = Wo^T.  (rows [1536,2040) come from wpe_kernel)
__global__ __launch_bounds__(256) void buildw(const float* __restrict__ Wq, const float* __restrict__ Wk,
                                              const float* __restrict__ Wv, const float* __restrict__ Wo,
                                              u16* __restrict__ WbigT, u16* __restrict__ WoT) {
  const float SCALE = 0.08838834764831845f;  // 1/sqrt(128)
  int row = blockIdx.x;  // 0..2055
  int t = threadIdx.x;
  if (row < 512) {
    for (int k = t; k < 512; k += 256) WbigT[row*512 + k] = f2b(Wq[k*512 + row] * SCALE);
  } else if (row < 1024) {
    int n = row - 512;
    for (int k = t; k < 512; k += 256) WbigT[row*512 + k] = f2b(Wk[k*512 + n]);
  } else if (row < 1536) {
    int n = row - 1024;
    for (int k = t; k < 512; k += 256) WbigT[row*512 + k] = f2b(Wv[k*512 + n]);
  } else if (row < 1544) {
    int rr = row - 1536 + 2040;
    for (int k = t; k < 512; k += 256) WbigT[rr*512 + k] = 0;
  } else {
    int n = row - 1544;
    for (int k = t; k < 512; k += 256) WoT[n*512 + k] = f2b(Wo[k*512 + n]);
  }
}

// WbigT rows [1536,1788): (Wq @ pe_w * scale)^T per head; [1788,2040): pe_h.
__global__ __launch_bounds__(256) void wpe_kernel(const float* __restrict__ Wq, const float* __restrict__ pew,
                                                  const float* __restrict__ peh, u16* __restrict__ WbigT) {
  int k = blockIdx.x;  // 0..511
  int t = threadIdx.x;
  __shared__ float wrow[512];
  for (int j = t; j < 512; j += 256) wrow[j] = Wq[k*512 + j];
  __syncthreads();
  if (t < 252) {
    int h = t / 63, r = t - h*63;
    float aw = 0.f, ah = 0.f;
    for (int d = 0; d < 128; d++) {
      float qv = wrow[h*128 + d];
      aw += qv * pew[d*63 + r];
      ah += qv * peh[d*63 + r];
    }
    const float SCALE = 0.08838834764831845f;
    WbigT[(size_t)(1536 + t)*512 + k] = f2b(aw * SCALE);
    WbigT[(size_t)(1788 + t)*512 + k] = f2b(ah * SCALE);
  }
}

// ---------------- GEMM (A row-major [M][512] bf16, Bt = B^T [N][512] bf16) ----------------
// 128x128 tile, 4 waves (2x2), 16x16x32 bf16 MFMA.
// 2-phase pipeline: double-buffered LDS, stage(next) issued BEFORE compute(cur),
// single __syncthreads (vmcnt drain) per K-step at the END -> load latency hides under compute.
template<int MODE>
__global__ __launch_bounds__(256) void gemm_bt(
    const u16* __restrict__ A, const u16* __restrict__ Bt,
    float* __restrict__ outF,
    u16* __restrict__ Qb, u16* __restrict__ Kb, u16* __restrict__ Vt,
    float* __restrict__ RELW, float* __restrict__ RELH)
{
  __shared__ char sm[65536];   // [p][As 16KB][Bs 16KB]
  const int tid = threadIdx.x;
  const int w = tid >> 6, l = tid & 63, g = l >> 4, c = l & 15;
  const int bm = blockIdx.x, bn = blockIdx.y;
  const int wm = (w >> 1) * 64, wn = (w & 1) * 64;

  f32x4 acc[4][4];
#pragma unroll
  for (int i = 0; i < 4; i++)
#pragma unroll
    for (int j = 0; j < 4; j++) acc[i][j] = f32x4{0.f, 0.f, 0.f, 0.f};

  const char* Ab = (const char*)A;
  const char* Bb = (const char*)Bt;
  const int rsub = l >> 3;
  const int csw = (((l & 7) ^ rsub) << 4);   // pre-swizzled source byte within 128B row-slice

#define G_STAGE(kb, p)                                                                    \
  {                                                                                       \
    char* As_ = sm + (p)*32768;                                                           \
    char* Bs_ = As_ + 16384;                                                              \
    const int kbyte = (kb) * 128;                                                         \
    _Pragma("unroll")                                                                     \
    for (int t = 0; t < 4; t++) {                                                         \
      const int row = (w*4 + t)*8 + rsub;                                                 \
      glds16(Ab + (size_t)(bm*128 + row) * 1024 + kbyte + csw, As_ + (w*4 + t)*1024);     \
      glds16(Bb + (size_t)(bn*128 + row) * 1024 + kbyte + csw, Bs_ + (w*4 + t)*1024);     \
    }                                                                                     \
  }

  G_STAGE(0, 0);
  __syncthreads();

  for (int kb = 0; kb < 8; kb++) {
    const int p = kb & 1;
    if (kb < 7) G_STAGE(kb + 1, p ^ 1);
    const char* As_ = sm + p*32768;
    const char* Bs_ = As_ + 16384;
#pragma unroll
    for (int ks = 0; ks < 2; ks++) {
      const int koff = (ks*64 + g*16) ^ ((c & 7) << 4);
      bf16x8 af[4], bfr[4];
#pragma unroll
      for (int mf = 0; mf < 4; mf++)
        af[mf] = *(const bf16x8*)(As_ + (wm + mf*16 + c)*128 + koff);
#pragma unroll
      for (int nf = 0; nf < 4; nf++)
        bfr[nf] = *(const bf16x8*)(Bs_ + (wn + nf*16 + c)*128 + koff);
#pragma unroll
      for (int mf = 0; mf < 4; mf++)
#pragma unroll
        for (int nf = 0; nf < 4; nf++)
          acc[mf][nf] = __builtin_amdgcn_mfma_f32_16x16x32_bf16(af[mf], bfr[nf], acc[mf][nf], 0, 0, 0);
    }
    __syncthreads();   // drains vmcnt (stage kb+1) + syncs buffers
  }

  if (MODE == 0) {
#pragma unroll
    for (int mf = 0; mf < 4; mf++) {
#pragma unroll
      for (int nf = 0; nf < 4; nf++) {
        const int n = bn*128 + wn + nf*16 + c;
#pragma unroll
        for (int r = 0; r < 4; r++) {
          const int m = bm*128 + wm + mf*16 + g*4 + r;
          outF[(size_t)m*512 + n] = acc[mf][nf][r];
        }
      }
    }
  } else {
#pragma unroll
    for (int mf = 0; mf < 4; mf++) {
#pragma unroll
      for (int nf = 0; nf < 4; nf++) {
        const int n = bn*128 + wn + nf*16 + c;
#pragma unroll
        for (int r = 0; r < 4; r++) {
          const int m = bm*128 + wm + mf*16 + g*4 + r;   // = b*1024 + i
          const int b = m >> 10, i = m & 1023;
          const float v = acc[mf][nf][r];
          if (n < 512) {
            int h = n >> 7, d = n & 127;
            Qb[(size_t)((b*4 + h)*1024 + i)*128 + d] = f2b(v);
          } else if (n < 1024) {
            int h = (n - 512) >> 7, d = n & 127;
            Kb[(size_t)((b*4 + h)*1024 + i)*128 + d] = f2b(v);
          } else if (n < 1536) {
            int h = (n - 1024) >> 7, d = n & 127;
            Vt[(size_t)((b*4 + h)*128 + d)*1024 + i] = f2b(v);
          } else if (n < 1788) {
            int q = n - 1536, h = q / 63, r2 = q - h*63;
            RELW[(size_t)((b*4 + h)*1024 + i)*64 + r2] = v;
          } else if (n < 2040) {
            int q = n - 1788, h = q / 63, r2 = q - h*63;
            RELH[(size_t)((b*4 + h)*1024 + i)*64 + r2] = v;
          }
        }
      }
    }
  }
#undef G_STAGE
}

// ---------------- fused flash attention with decomposed relative bias ----------------
// grid (32 bh, 16 q-tiles), 256 threads (4 waves x 16 Q-rows).
// KV tiles of 64, double-buffered (2-phase pipeline), setprio around MFMA clusters.
__global__ __launch_bounds__(256) void attn_fused(
    const u16* __restrict__ Qb, const u16* __restrict__ Kb, const u16* __restrict__ Vt,
    const float* __restrict__ RELW, const float* __restrict__ RELH,
    u16* __restrict__ AO)
{
  // layout: [p][Kt 16KB][Vts 16KB] x2, then Pl 8KB  -> 72KB
  __shared__ char sm[73728];
  char* const Pl = sm + 65536;
  const int tid = threadIdx.x;
  const int w = tid >> 6, l = tid & 63, g = l >> 4, c = l & 15;
  const int bh = blockIdx.x, qt = blockIdx.y;
  const int i0 = qt * 64;

  // Q fragments for this wave's 16 rows: A-frag row = c, k = s*32 + g*8 + [0,8)
  bf16x8 qf[4];
  {
    const char* qbase = (const char*)Qb + (size_t)(bh*1024 + i0 + w*16 + c) * 256;
#pragma unroll
    for (int s = 0; s < 4; s++) qf[s] = *(const bf16x8*)(qbase + s*64 + g*16);
  }

  f32x4 Oacc[8];
#pragma unroll
  for (int fd = 0; fd < 8; fd++) Oacc[fd] = f32x4{0.f, 0.f, 0.f, 0.f};
  float mrow[4] = {-INFINITY, -INFINITY, -INFINITY, -INFINITY};
  float lrow[4] = {0.f, 0.f, 0.f, 0.f};

  // stage one 64-row K/V tile into buffer p (K: [64][128] swz, V^T: [128][64] swz)
#define A_STAGE(jt, p)                                                                     \
  {                                                                                        \
    char* Kt_ = sm + (p)*32768;                                                            \
    char* Vs_ = Kt_ + 16384;                                                               \
    const int j0b = (jt) * 64;                                                             \
    _Pragma("unroll")                                                                      \
    for (int t = 0; t < 4; t++) {                                                          \
      const int L = (w*4 + t)*1024 + l*16;                                                 \
      const int jr = L >> 8, jb = L & 255;                                                 \
      glds16((const char*)Kb + (size_t)(bh*1024 + j0b + jr) * 256 + (jb ^ ((jr & 7) << 4)),\
             Kt_ + L);                                                                     \
      const int dr = L >> 7, db = L & 127;                                                 \
      glds16((const char*)Vt + (size_t)(bh*128 + dr) * 2048 + j0b*2 + (db ^ ((dr & 7) << 4)),\
             Vs_ + L);                                                                     \
    }                                                                                      \
  }

  A_STAGE(0, 0);
  __syncthreads();

  for (int jt = 0; jt < 16; jt++) {
    const int p = jt & 1;
    if (jt < 15) A_STAGE(jt + 1, p ^ 1);
    const char* Kt_ = sm + p*32768;
    const char* Vs_ = Kt_ + 16384;

    // S = Q K^T for this 64-col tile: acc[fn] covers cols fn*16..+16
    f32x4 acc[4];
#pragma unroll
    for (int fn = 0; fn < 4; fn++) acc[fn] = f32x4{0.f, 0.f, 0.f, 0.f};
    __builtin_amdgcn_s_setprio(1);
#pragma unroll
    for (int s = 0; s < 4; s++) {
      const int koff = (s*64 + g*16) ^ ((c & 7) << 4);
#pragma unroll
      for (int fn = 0; fn < 4; fn++) {
        bf16x8 kf = *(const bf16x8*)(Kt_ + (fn*16 + c)*256 + koff);
        acc[fn] = __builtin_amdgcn_mfma_f32_16x16x32_bf16(qf[s], kf, acc[fn], 0, 0, 0);
      }
    }
    __builtin_amdgcn_s_setprio(0);

    // bias + online softmax (C-frag: row = g*4+r, col = fn*16+c)
    // j = jt*64 + fn*16 + c  ->  xj = (fn&1)*16 + c,  yj = jt*2 + (fn>>1)
#pragma unroll
    for (int r = 0; r < 4; r++) {
      const int i = i0 + w*16 + g*4 + r;
      const int xi = i & 31, yi = i >> 5;
      const float* rw = RELW + ((size_t)(bh*1024 + i) << 6);
      const float* rh = RELH + ((size_t)(bh*1024 + i) << 6);
      const float xw0 = rw[c - xi + 31];
      const float xw1 = rw[c + 16 - xi + 31];
      const float yh0 = rh[jt*2 - yi + 31];
      const float yh1 = rh[jt*2 + 1 - yi + 31];
      float mx = -INFINITY;
#pragma unroll
      for (int fn = 0; fn < 4; fn++) {
        float sb = acc[fn][r] + ((fn & 1) ? xw1 : xw0) + ((fn >> 1) ? yh1 : yh0);
        acc[fn][r] = sb;
        mx = fmaxf(mx, sb);
      }
      mx = fmaxf(mx, __shfl_xor(mx, 1));
      mx = fmaxf(mx, __shfl_xor(mx, 2));
      mx = fmaxf(mx, __shfl_xor(mx, 4));
      mx = fmaxf(mx, __shfl_xor(mx, 8));
      const float mnew = fmaxf(mrow[r], mx);
      const float sc = __expf(mrow[r] - mnew);
      mrow[r] = mnew;
      float ps = 0.f;
      const int rowl = g*4 + r;
      char* pb = Pl + w*2048 + rowl*128;
      const int swz = (rowl & 7) << 4;
#pragma unroll
      for (int fn = 0; fn < 4; fn++) {
        float pval = __expf(acc[fn][r] - mnew);
        ps += pval;
        *(u16*)(pb + (((fn*16 + c)*2) ^ swz)) = f2b(pval);
      }
      ps += __shfl_xor(ps, 1);
      ps += __shfl_xor(ps, 2);
      ps += __shfl_xor(ps, 4);
      ps += __shfl_xor(ps, 8);
      lrow[r] = lrow[r] * sc + ps;
#pragma unroll
      for (int fd = 0; fd < 8; fd++) Oacc[fd][r] *= sc;
    }

    // O += P V   (A-frag of P: row = c, k(=j) = s*32 + g*8)
    __builtin_amdgcn_s_setprio(1);
#pragma unroll
    for (int s = 0; s < 2; s++) {
      const int koff = (s*64 + g*16) ^ ((c & 7) << 4);
      bf16x8 pf = *(const bf16x8*)(Pl + w*2048 + c*128 + koff);
#pragma unroll
      for (int fd = 0; fd < 8; fd++) {
        bf16x8 vf = *(const bf16x8*)(Vs_ + (fd*16 + c)*128 + koff);
        Oacc[fd] = __builtin_amdgcn_mfma_f32_16x16x32_bf16(pf, vf, Oacc[fd], 0, 0, 0);
      }
    }
    __builtin_amdgcn_s_setprio(0);
    __syncthreads();   // drains vmcnt (stage jt+1) + syncs buffers
  }

  const int b = bh >> 2, h = bh & 3;
#pragma unroll
  for (int fd = 0; fd < 8; fd++) {
#pragma unroll
    for (int r = 0; r < 4; r++) {
      const int i = i0 + w*16 + g*4 + r;
      AO[(size_t)(b*1024 + i)*512 + h*128 + fd*16 + c] = f2b(Oacc[fd][r] / lrow[r]);
    }
  }
#undef A_STAGE
}

// ---------------- launcher ----------------
extern "C" void kernel_launch(void* const* d_in, const int* in_sizes, int n_in,
                              void* d_out, int out_size, void* d_ws, size_t ws_size,
                              hipStream_t stream) {
  const float* x   = (const float*)d_in[0];
  const float* Wq  = (const float*)d_in[1];
  const float* Wk  = (const float*)d_in[2];
  const float* Wv  = (const float*)d_in[3];
  const float* Wo  = (const float*)d_in[4];
  const float* pew = (const float*)d_in[5];
  const float* peh = (const float*)d_in[6];

  char* ws = (char*)d_ws;
  u16* xb    = (u16*)ws;    ws += (size_t)8192*512*2;
  u16* WbigT = (u16*)ws;    ws += (size_t)2048*512*2;
  u16* WoT   = (u16*)ws;    ws += (size_t)512*512*2;
  u16* Qb    = (u16*)ws;    ws += (size_t)32*1024*128*2;
  u16* Kb    = (u16*)ws;    ws += (size_t)32*1024*128*2;
  u16* Vt    = (u16*)ws;    ws += (size_t)32*1024*128*2;
  float* RELW = (float*)ws; ws += (size_t)32*1024*64*4;
  float* RELH = (float*)ws; ws += (size_t)32*1024*64*4;
  u16* AO    = (u16*)ws;    ws += (size_t)8192*512*2;

  castx<<<4096, 256, 0, stream>>>(x, xb);
  buildw<<<2056, 256, 0, stream>>>(Wq, Wk, Wv, Wo, WbigT, WoT);
  wpe_kernel<<<512, 256, 0, stream>>>(Wq, pew, peh, WbigT);
  gemm_bt<1><<<dim3(64, 16), 256, 0, stream>>>(xb, WbigT, nullptr, Qb, Kb, Vt, RELW, RELH);
  attn_fused<<<dim3(32, 16), 256, 0, stream>>>(Qb, Kb, Vt, RELW, RELH, AO);
  gemm_bt<0><<<dim3(64, 4), 256, 0, stream>>>(AO, WoT, (float*)d_out,
                                              nullptr, nullptr, nullptr, nullptr, nullptr);
}

// Round 3
// 114.851 us; speedup vs baseline: 1.1162x; 1.1019x over previous
//
#include <hip/hip_runtime.h>
#include <math.h>

typedef unsigned short u16;
typedef unsigned int u32;
typedef __bf16 bf16x8 __attribute__((ext_vector_type(8)));
typedef float f32x4 __attribute__((ext_vector_type(4)));

__device__ __forceinline__ u16 f2b(float f) {
  u32 u = __builtin_bit_cast(u32, f);
  u32 r = (u + 0x7FFFu + ((u >> 16) & 1u)) >> 16;
  return (u16)r;
}

__device__ __forceinline__ void glds16(const void* g, void* lds) {
  __builtin_amdgcn_global_load_lds(
      (const __attribute__((address_space(1))) void*)(void*)(const_cast<void*>(g)),
      (__attribute__((address_space(3))) void*)lds, 16, 0, 0);
}

// ---------------- prep kernels ----------------

__global__ __launch_bounds__(256) void castx(const float* __restrict__ x, u16* __restrict__ xb) {
  int idx = blockIdx.x * 256 + threadIdx.x;
  float4 v = ((const float4*)x)[idx];
  ushort4 o;
  o.x = f2b(v.x); o.y = f2b(v.y); o.z = f2b(v.z); o.w = f2b(v.w);
  ((ushort4*)xb)[idx] = o;
}

__global__ __launch_bounds__(256) void buildw(const float* __restrict__ Wq, const float* __restrict__ Wk,
                                              const float* __restrict__ Wv, const float* __restrict__ Wo,
                                              u16* __restrict__ WbigT, u16* __restrict__ WoT) {
  const float SCALE = 0.08838834764831845f;  // 1/sqrt(128)
  int row = blockIdx.x;  // 0..2055
  int t = threadIdx.x;
  if (row < 512) {
    for (int k = t; k < 512; k += 256) WbigT[row*512 + k] = f2b(Wq[k*512 + row] * SCALE);
  } else if (row < 1024) {
    int n = row - 512;
    for (int k = t; k < 512; k += 256) WbigT[row*512 + k] = f2b(Wk[k*512 + n]);
  } else if (row < 1536) {
    int n = row - 1024;
    for (int k = t; k < 512; k += 256) WbigT[row*512 + k] = f2b(Wv[k*512 + n]);
  } else if (row < 1544) {
    int rr = row - 1536 + 2040;
    for (int k = t; k < 512; k += 256) WbigT[rr*512 + k] = 0;
  } else {
    int n = row - 1544;
    for (int k = t; k < 512; k += 256) WoT[n*512 + k] = f2b(Wo[k*512 + n]);
  }
}

__global__ __launch_bounds__(256) void wpe_kernel(const float* __restrict__ Wq, const float* __restrict__ pew,
                                                  const float* __restrict__ peh, u16* __restrict__ WbigT) {
  int k = blockIdx.x;  // 0..511
  int t = threadIdx.x;
  __shared__ float wrow[512];
  for (int j = t; j < 512; j += 256) wrow[j] = Wq[k*512 + j];
  __syncthreads();
  if (t < 252) {
    int h = t / 63, r = t - h*63;
    float aw = 0.f, ah = 0.f;
    for (int d = 0; d < 128; d++) {
      float qv = wrow[h*128 + d];
      aw += qv * pew[d*63 + r];
      ah += qv * peh[d*63 + r];
    }
    const float SCALE = 0.08838834764831845f;
    WbigT[(size_t)(1536 + t)*512 + k] = f2b(aw * SCALE);
    WbigT[(size_t)(1788 + t)*512 + k] = f2b(ah * SCALE);
  }
}

// ---------------- GEMM (A row-major [M][512] bf16, Bt = B^T [N][512] bf16) ----------------
// 128x128 tile, 4 waves (2x2), 16x16x32 bf16 MFMA.
// 2-deep pipeline: fully unrolled K-loop (constant LDS offsets), raw s_barrier,
// counted s_waitcnt vmcnt(8) -> loads span two compute phases, never drained in-loop.
template<int MODE>
__global__ __launch_bounds__(256) void gemm_bt(
    const u16* __restrict__ A, const u16* __restrict__ Bt,
    float* __restrict__ outF,
    u16* __restrict__ Qb, u16* __restrict__ Kb, u16* __restrict__ Vt,
    float* __restrict__ RELW, float* __restrict__ RELH)
{
  __shared__ char sm[65536];   // [p][As 16KB][Bs 16KB]
  const int tid = threadIdx.x;
  const int w = tid >> 6, l = tid & 63, g = l >> 4, c = l & 15;
  const int bm = blockIdx.x, bn = blockIdx.y;
  const int wm = (w >> 1) * 64, wn = (w & 1) * 64;

  f32x4 acc[4][4];
#pragma unroll
  for (int i = 0; i < 4; i++)
#pragma unroll
    for (int j = 0; j < 4; j++) acc[i][j] = f32x4{0.f, 0.f, 0.f, 0.f};

  const char* Ab = (const char*)A;
  const char* Bb = (const char*)Bt;
  const int rsub = l >> 3;
  const int csw = (((l & 7) ^ rsub) << 4);   // pre-swizzled source byte within 128B row-slice

#define G_STAGE(kb, p)                                                                    \
  {                                                                                       \
    char* As_ = sm + (p)*32768;                                                           \
    char* Bs_ = As_ + 16384;                                                              \
    const int kbyte = (kb) * 128;                                                         \
    _Pragma("unroll")                                                                     \
    for (int t = 0; t < 4; t++) {                                                         \
      const int row = (w*4 + t)*8 + rsub;                                                 \
      glds16(Ab + (size_t)(bm*128 + row) * 1024 + kbyte + csw, As_ + (w*4 + t)*1024);     \
      glds16(Bb + (size_t)(bn*128 + row) * 1024 + kbyte + csw, Bs_ + (w*4 + t)*1024);     \
    }                                                                                     \
  }

  G_STAGE(0, 0);
  G_STAGE(1, 1);

#pragma unroll
  for (int kb = 0; kb < 8; kb++) {
    const int p = kb & 1;
    if (kb < 7) { asm volatile("s_waitcnt vmcnt(8)" ::: "memory"); }
    else        { asm volatile("s_waitcnt vmcnt(0)" ::: "memory"); }
    __builtin_amdgcn_s_barrier();
    const char* As_ = sm + p*32768;
    const char* Bs_ = As_ + 16384;
#pragma unroll
    for (int ks = 0; ks < 2; ks++) {
      const int koff = (ks*64 + g*16) ^ ((c & 7) << 4);
      bf16x8 af[4], bfr[4];
#pragma unroll
      for (int mf = 0; mf < 4; mf++)
        af[mf] = *(const bf16x8*)(As_ + (wm + mf*16 + c)*128 + koff);
#pragma unroll
      for (int nf = 0; nf < 4; nf++)
        bfr[nf] = *(const bf16x8*)(Bs_ + (wn + nf*16 + c)*128 + koff);
#pragma unroll
      for (int mf = 0; mf < 4; mf++)
#pragma unroll
        for (int nf = 0; nf < 4; nf++)
          acc[mf][nf] = __builtin_amdgcn_mfma_f32_16x16x32_bf16(af[mf], bfr[nf], acc[mf][nf], 0, 0, 0);
    }
    __builtin_amdgcn_s_barrier();           // all waves done reading buf p
    if (kb < 6) G_STAGE(kb + 2, p);         // safe to overwrite buf p
  }

  if (MODE == 0) {
#pragma unroll
    for (int mf = 0; mf < 4; mf++) {
#pragma unroll
      for (int nf = 0; nf < 4; nf++) {
        const int n = bn*128 + wn + nf*16 + c;
#pragma unroll
        for (int r = 0; r < 4; r++) {
          const int m = bm*128 + wm + mf*16 + g*4 + r;
          outF[(size_t)m*512 + n] = acc[mf][nf][r];
        }
      }
    }
  } else if (bn >= 8 && bn < 12) {
    // pure-V block: transpose 128x128 via LDS (XOR swizzle), store [d][i] coalesced
    char* T = sm;   // 32KB, byte = d2*256 + ((i*2) ^ ((d2&7)<<4))
#pragma unroll
    for (int mf = 0; mf < 4; mf++) {
#pragma unroll
      for (int nf = 0; nf < 4; nf++) {
        const int d2 = wn + nf*16 + c;
        const int swz = (d2 & 7) << 4;
#pragma unroll
        for (int r = 0; r < 4; r++) {
          const int i = wm + mf*16 + g*4 + r;
          *(u16*)(T + d2*256 + ((i*2) ^ swz)) = f2b(acc[mf][nf][r]);
        }
      }
    }
    __builtin_amdgcn_s_barrier();
    const int b = bm >> 3, h = bn - 8;
#pragma unroll
    for (int it = 0; it < 8; it++) {
      const int L = it*4096 + tid*16;
      const int d2 = L >> 8, kk = L & 255;
      const int swz = (d2 & 7) << 4;
      bf16x8 vv = *(const bf16x8*)(T + d2*256 + (kk ^ swz));
      char* dst = (char*)Vt + ((size_t)((b*4 + h)*128 + d2) * 1024 + (size_t)(bm & 7)*128) * 2 + kk;
      *(bf16x8*)dst = vv;
    }
  } else {
#pragma unroll
    for (int mf = 0; mf < 4; mf++) {
#pragma unroll
      for (int nf = 0; nf < 4; nf++) {
        const int n = bn*128 + wn + nf*16 + c;
#pragma unroll
        for (int r = 0; r < 4; r++) {
          const int m = bm*128 + wm + mf*16 + g*4 + r;   // = b*1024 + i
          const int b = m >> 10, i = m & 1023;
          const float v = acc[mf][nf][r];
          if (n < 512) {
            int h = n >> 7, d = n & 127;
            Qb[(size_t)((b*4 + h)*1024 + i)*128 + d] = f2b(v);
          } else if (n < 1024) {
            int h = (n - 512) >> 7, d = n & 127;
            Kb[(size_t)((b*4 + h)*1024 + i)*128 + d] = f2b(v);
          } else if (n >= 1536 && n < 1788) {
            int q = n - 1536, h = q / 63, r2 = q - h*63;
            RELW[(size_t)((b*4 + h)*1024 + i)*64 + r2] = v;
          } else if (n >= 1788 && n < 2040) {
            int q = n - 1788, h = q / 63, r2 = q - h*63;
            RELH[(size_t)((b*4 + h)*1024 + i)*64 + r2] = v;
          }
        }
      }
    }
  }
#undef G_STAGE
}

// ---------------- fused flash attention with decomposed relative bias ----------------
// grid (32 bh, 16 q-tiles), 256 threads (4 waves x 16 Q-rows).
// KV tiles of 64, 2-deep pipeline (counted vmcnt + raw barriers), bias hoisted/prefetched.
__global__ __launch_bounds__(256) void attn_fused(
    const u16* __restrict__ Qb, const u16* __restrict__ Kb, const u16* __restrict__ Vt,
    const float* __restrict__ RELW, const float* __restrict__ RELH,
    u16* __restrict__ AO)
{
  __shared__ char sm[73728];   // [p][Kt 16KB][Vts 16KB] x2, Pl 8KB
  char* const Pl = sm + 65536;
  const int tid = threadIdx.x;
  const int w = tid >> 6, l = tid & 63, g = l >> 4, c = l & 15;
  const int bh = blockIdx.x, qt = blockIdx.y;
  const int i0 = qt * 64;

  bf16x8 qf[4];
  {
    const char* qbase = (const char*)Qb + (size_t)(bh*1024 + i0 + w*16 + c) * 256;
#pragma unroll
    for (int s = 0; s < 4; s++) qf[s] = *(const bf16x8*)(qbase + s*64 + g*16);
  }

  // hoisted bias state: xw constant over jt; yh base pointer per row
  float xw0h[4], xw1h[4];
  const float* rhbase[4];
#pragma unroll
  for (int r = 0; r < 4; r++) {
    const int i = i0 + w*16 + g*4 + r;
    const int xi = i & 31, yi = i >> 5;
    const float* rw = RELW + ((size_t)(bh*1024 + i) << 6);
    xw0h[r] = rw[c - xi + 31];
    xw1h[r] = rw[c + 16 - xi + 31];
    rhbase[r] = RELH + ((size_t)(bh*1024 + i) << 6) + (31 - yi);
  }

  f32x4 Oacc[8];
#pragma unroll
  for (int fd = 0; fd < 8; fd++) Oacc[fd] = f32x4{0.f, 0.f, 0.f, 0.f};
  float mrow[4] = {-INFINITY, -INFINITY, -INFINITY, -INFINITY};
  float lrow[4] = {0.f, 0.f, 0.f, 0.f};

#define A_STAGE(jt, p)                                                                     \
  {                                                                                        \
    char* Kt_ = sm + (p)*32768;                                                            \
    char* Vs_ = Kt_ + 16384;                                                               \
    const int j0b = (jt) * 64;                                                             \
    _Pragma("unroll")                                                                      \
    for (int t = 0; t < 4; t++) {                                                          \
      const int L = (w*4 + t)*1024 + l*16;                                                 \
      const int jr = L >> 8, jb = L & 255;                                                 \
      glds16((const char*)Kb + (size_t)(bh*1024 + j0b + jr) * 256 + (jb ^ ((jr & 7) << 4)),\
             Kt_ + L);                                                                     \
      const int dr = L >> 7, db = L & 127;                                                 \
      glds16((const char*)Vt + (size_t)(bh*128 + dr) * 2048 + j0b*2 + (db ^ ((dr & 7) << 4)),\
             Vs_ + L);                                                                     \
    }                                                                                      \
  }

  A_STAGE(0, 0);
  A_STAGE(1, 1);

#pragma unroll 2
  for (int jt = 0; jt < 16; jt++) {
    const int p = jt & 1;
    if (jt < 15) { asm volatile("s_waitcnt vmcnt(8)" ::: "memory"); }
    else         { asm volatile("s_waitcnt vmcnt(0)" ::: "memory"); }
    __builtin_amdgcn_s_barrier();

    // bias prefetch for this jt (after the wait so vmcnt counting stays exact;
    // latency hides under the QK MFMA cluster)
    float yh0v[4], yh1v[4];
#pragma unroll
    for (int r = 0; r < 4; r++) { yh0v[r] = rhbase[r][jt*2]; yh1v[r] = rhbase[r][jt*2 + 1]; }

    const char* Kt_ = sm + p*32768;
    const char* Vs_ = Kt_ + 16384;

    // S = Q K^T
    f32x4 acc[4];
#pragma unroll
    for (int fn = 0; fn < 4; fn++) acc[fn] = f32x4{0.f, 0.f, 0.f, 0.f};
    __builtin_amdgcn_s_setprio(1);
#pragma unroll
    for (int s = 0; s < 4; s++) {
      const int koff = (s*64 + g*16) ^ ((c & 7) << 4);
#pragma unroll
      for (int fn = 0; fn < 4; fn++) {
        bf16x8 kf = *(const bf16x8*)(Kt_ + (fn*16 + c)*256 + koff);
        acc[fn] = __builtin_amdgcn_mfma_f32_16x16x32_bf16(qf[s], kf, acc[fn], 0, 0, 0);
      }
    }
    __builtin_amdgcn_s_setprio(0);

    // bias + online softmax (C-frag: row = g*4+r, col = fn*16+c)
#pragma unroll
    for (int r = 0; r < 4; r++) {
      float mx = -INFINITY;
#pragma unroll
      for (int fn = 0; fn < 4; fn++) {
        float sb = acc[fn][r] + ((fn & 1) ? xw1h[r] : xw0h[r]) + ((fn >> 1) ? yh1v[r] : yh0v[r]);
        acc[fn][r] = sb;
        mx = fmaxf(mx, sb);
      }
      mx = fmaxf(mx, __shfl_xor(mx, 1));
      mx = fmaxf(mx, __shfl_xor(mx, 2));
      mx = fmaxf(mx, __shfl_xor(mx, 4));
      mx = fmaxf(mx, __shfl_xor(mx, 8));
      const float mnew = fmaxf(mrow[r], mx);
      const float sc = __expf(mrow[r] - mnew);
      mrow[r] = mnew;
      float ps = 0.f;
      const int rowl = g*4 + r;
      char* pb = Pl + w*2048 + rowl*128;
      const int swz = (rowl & 7) << 4;
#pragma unroll
      for (int fn = 0; fn < 4; fn++) {
        float pval = __expf(acc[fn][r] - mnew);
        ps += pval;
        *(u16*)(pb + (((fn*16 + c)*2) ^ swz)) = f2b(pval);
      }
      ps += __shfl_xor(ps, 1);
      ps += __shfl_xor(ps, 2);
      ps += __shfl_xor(ps, 4);
      ps += __shfl_xor(ps, 8);
      lrow[r] = lrow[r] * sc + ps;
#pragma unroll
      for (int fd = 0; fd < 8; fd++) Oacc[fd][r] *= sc;
    }

    // O += P V
    __builtin_amdgcn_s_setprio(1);
#pragma unroll
    for (int s = 0; s < 2; s++) {
      const int koff = (s*64 + g*16) ^ ((c & 7) << 4);
      bf16x8 pf = *(const bf16x8*)(Pl + w*2048 + c*128 + koff);
#pragma unroll
      for (int fd = 0; fd < 8; fd++) {
        bf16x8 vf = *(const bf16x8*)(Vs_ + (fd*16 + c)*128 + koff);
        Oacc[fd] = __builtin_amdgcn_mfma_f32_16x16x32_bf16(pf, vf, Oacc[fd], 0, 0, 0);
      }
    }
    __builtin_amdgcn_s_setprio(0);

    __builtin_amdgcn_s_barrier();           // all waves done reading buf p
    if (jt < 14) A_STAGE(jt + 2, p);        // safe to overwrite buf p
  }

  const int b = bh >> 2, h = bh & 3;
#pragma unroll
  for (int fd = 0; fd < 8; fd++) {
#pragma unroll
    for (int r = 0; r < 4; r++) {
      const int i = i0 + w*16 + g*4 + r;
      AO[(size_t)(b*1024 + i)*512 + h*128 + fd*16 + c] = f2b(Oacc[fd][r] / lrow[r]);
    }
  }
#undef A_STAGE
}

// ---------------- launcher ----------------
extern "C" void kernel_launch(void* const* d_in, const int* in_sizes, int n_in,
                              void* d_out, int out_size, void* d_ws, size_t ws_size,
                              hipStream_t stream) {
  const float* x   = (const float*)d_in[0];
  const float* Wq  = (const float*)d_in[1];
  const float* Wk  = (const float*)d_in[2];
  const float* Wv  = (const float*)d_in[3];
  const float* Wo  = (const float*)d_in[4];
  const float* pew = (const float*)d_in[5];
  const float* peh = (const float*)d_in[6];

  char* ws = (char*)d_ws;
  u16* xb    = (u16*)ws;    ws += (size_t)8192*512*2;
  u16* WbigT = (u16*)ws;    ws += (size_t)2048*512*2;
  u16* WoT   = (u16*)ws;    ws += (size_t)512*512*2;
  u16* Qb    = (u16*)ws;    ws += (size_t)32*1024*128*2;
  u16* Kb    = (u16*)ws;    ws += (size_t)32*1024*128*2;
  u16* Vt    = (u16*)ws;    ws += (size_t)32*1024*128*2;
  float* RELW = (float*)ws; ws += (size_t)32*1024*64*4;
  float* RELH = (float*)ws; ws += (size_t)32*1024*64*4;
  u16* AO    = (u16*)ws;    ws += (size_t)8192*512*2;

  castx<<<4096, 256, 0, stream>>>(x, xb);
  buildw<<<2056, 256, 0, stream>>>(Wq, Wk, Wv, Wo, WbigT, WoT);
  wpe_kernel<<<512, 256, 0, stream>>>(Wq, pew, peh, WbigT);
  gemm_bt<1><<<dim3(64, 16), 256, 0, stream>>>(xb, WbigT, nullptr, Qb, Kb, Vt, RELW, RELH);
  attn_fused<<<dim3(32, 16), 256, 0, stream>>>(Qb, Kb, Vt, RELW, RELH, AO);
  gemm_bt<0><<<dim3(64, 4), 256, 0, stream>>>(AO, WoT, (float*)d_out,
                                              nullptr, nullptr, nullptr, nullptr, nullptr);
}

// Round 4
// 104.546 us; speedup vs baseline: 1.2263x; 1.0986x over previous
//
#include <hip/hip_runtime.h>
#include <math.h>

typedef unsigned short u16;
typedef unsigned int u32;
typedef __bf16 bf16x8 __attribute__((ext_vector_type(8)));
typedef float f32x4 __attribute__((ext_vector_type(4)));

__device__ __forceinline__ u16 f2b(float f) {
  u32 u = __builtin_bit_cast(u32, f);
  u32 r = (u + 0x7FFFu + ((u >> 16) & 1u)) >> 16;
  return (u16)r;
}

__device__ __forceinline__ void glds16(const void* g, void* lds) {
  __builtin_amdgcn_global_load_lds(
      (const __attribute__((address_space(1))) void*)(void*)(const_cast<void*>(g)),
      (__attribute__((address_space(3))) void*)lds, 16, 0, 0);
}

// ---------------- prep kernels ----------------

__global__ __launch_bounds__(256) void castx(const float* __restrict__ x, u16* __restrict__ xb) {
  int idx = blockIdx.x * 256 + threadIdx.x;
  float4 v = ((const float4*)x)[idx];
  ushort4 o;
  o.x = f2b(v.x); o.y = f2b(v.y); o.z = f2b(v.z); o.w = f2b(v.w);
  ((ushort4*)xb)[idx] = o;
}

__global__ __launch_bounds__(256) void buildw(const float* __restrict__ Wq, const float* __restrict__ Wk,
                                              const float* __restrict__ Wv, const float* __restrict__ Wo,
                                              u16* __restrict__ WbigT, u16* __restrict__ WoT) {
  const float SCALE = 0.08838834764831845f;  // 1/sqrt(128)
  int row = blockIdx.x;  // 0..2055
  int t = threadIdx.x;
  if (row < 512) {
    for (int k = t; k < 512; k += 256) WbigT[row*512 + k] = f2b(Wq[k*512 + row] * SCALE);
  } else if (row < 1024) {
    int n = row - 512;
    for (int k = t; k < 512; k += 256) WbigT[row*512 + k] = f2b(Wk[k*512 + n]);
  } else if (row < 1536) {
    int n = row - 1024;
    for (int k = t; k < 512; k += 256) WbigT[row*512 + k] = f2b(Wv[k*512 + n]);
  } else if (row < 1544) {
    int rr = row - 1536 + 2040;
    for (int k = t; k < 512; k += 256) WbigT[rr*512 + k] = 0;
  } else {
    int n = row - 1544;
    for (int k = t; k < 512; k += 256) WoT[n*512 + k] = f2b(Wo[k*512 + n]);
  }
}

__global__ __launch_bounds__(256) void wpe_kernel(const float* __restrict__ Wq, const float* __restrict__ pew,
                                                  const float* __restrict__ peh, u16* __restrict__ WbigT) {
  int k = blockIdx.x;  // 0..511
  int t = threadIdx.x;
  __shared__ float wrow[512];
  for (int j = t; j < 512; j += 256) wrow[j] = Wq[k*512 + j];
  __syncthreads();
  if (t < 252) {
    int h = t / 63, r = t - h*63;
    float aw = 0.f, ah = 0.f;
    for (int d = 0; d < 128; d++) {
      float qv = wrow[h*128 + d];
      aw += qv * pew[d*63 + r];
      ah += qv * peh[d*63 + r];
    }
    const float SCALE = 0.08838834764831845f;
    WbigT[(size_t)(1536 + t)*512 + k] = f2b(aw * SCALE);
    WbigT[(size_t)(1788 + t)*512 + k] = f2b(ah * SCALE);
  }
}

// ---------------- GEMM (A row-major [M][512] bf16, Bt = B^T [N][512] bf16) ----------------
// 128x128 tile, 4 waves (2x2), 16x16x32 bf16 MFMA.
// 2-deep pipeline: fully unrolled K-loop, raw s_barrier, counted vmcnt(8).
template<int MODE>
__global__ __launch_bounds__(256) void gemm_bt(
    const u16* __restrict__ A, const u16* __restrict__ Bt,
    float* __restrict__ outF,
    u16* __restrict__ Qb, u16* __restrict__ Kb, u16* __restrict__ Vt,
    float* __restrict__ RELW, float* __restrict__ RELH)
{
  __shared__ char sm[65536];   // [p][As 16KB][Bs 16KB]
  const int tid = threadIdx.x;
  const int w = tid >> 6, l = tid & 63, g = l >> 4, c = l & 15;
  const int bm = blockIdx.x, bn = blockIdx.y;
  const int wm = (w >> 1) * 64, wn = (w & 1) * 64;

  f32x4 acc[4][4];
#pragma unroll
  for (int i = 0; i < 4; i++)
#pragma unroll
    for (int j = 0; j < 4; j++) acc[i][j] = f32x4{0.f, 0.f, 0.f, 0.f};

  const char* Ab = (const char*)A;
  const char* Bb = (const char*)Bt;
  const int rsub = l >> 3;
  const int csw = (((l & 7) ^ rsub) << 4);

#define G_STAGE(kb, p)                                                                    \
  {                                                                                       \
    char* As_ = sm + (p)*32768;                                                           \
    char* Bs_ = As_ + 16384;                                                              \
    const int kbyte = (kb) * 128;                                                         \
    _Pragma("unroll")                                                                     \
    for (int t = 0; t < 4; t++) {                                                         \
      const int row = (w*4 + t)*8 + rsub;                                                 \
      glds16(Ab + (size_t)(bm*128 + row) * 1024 + kbyte + csw, As_ + (w*4 + t)*1024);     \
      glds16(Bb + (size_t)(bn*128 + row) * 1024 + kbyte + csw, Bs_ + (w*4 + t)*1024);     \
    }                                                                                     \
  }

  G_STAGE(0, 0);
  G_STAGE(1, 1);

#pragma unroll
  for (int kb = 0; kb < 8; kb++) {
    const int p = kb & 1;
    if (kb < 7) { asm volatile("s_waitcnt vmcnt(8)" ::: "memory"); }
    else        { asm volatile("s_waitcnt vmcnt(0)" ::: "memory"); }
    __builtin_amdgcn_s_barrier();
    const char* As_ = sm + p*32768;
    const char* Bs_ = As_ + 16384;
#pragma unroll
    for (int ks = 0; ks < 2; ks++) {
      const int koff = (ks*64 + g*16) ^ ((c & 7) << 4);
      bf16x8 af[4], bfr[4];
#pragma unroll
      for (int mf = 0; mf < 4; mf++)
        af[mf] = *(const bf16x8*)(As_ + (wm + mf*16 + c)*128 + koff);
#pragma unroll
      for (int nf = 0; nf < 4; nf++)
        bfr[nf] = *(const bf16x8*)(Bs_ + (wn + nf*16 + c)*128 + koff);
#pragma unroll
      for (int mf = 0; mf < 4; mf++)
#pragma unroll
        for (int nf = 0; nf < 4; nf++)
          acc[mf][nf] = __builtin_amdgcn_mfma_f32_16x16x32_bf16(af[mf], bfr[nf], acc[mf][nf], 0, 0, 0);
    }
    __builtin_amdgcn_s_barrier();
    if (kb < 6) G_STAGE(kb + 2, p);
  }

  if (MODE == 0) {
#pragma unroll
    for (int mf = 0; mf < 4; mf++) {
#pragma unroll
      for (int nf = 0; nf < 4; nf++) {
        const int n = bn*128 + wn + nf*16 + c;
#pragma unroll
        for (int r = 0; r < 4; r++) {
          const int m = bm*128 + wm + mf*16 + g*4 + r;
          outF[(size_t)m*512 + n] = acc[mf][nf][r];
        }
      }
    }
  } else if (bn >= 8 && bn < 12) {
    // pure-V block: transpose 128x128 via LDS (XOR swizzle), store [d][i] coalesced
    char* T = sm;
#pragma unroll
    for (int mf = 0; mf < 4; mf++) {
#pragma unroll
      for (int nf = 0; nf < 4; nf++) {
        const int d2 = wn + nf*16 + c;
        const int swz = (d2 & 7) << 4;
#pragma unroll
        for (int r = 0; r < 4; r++) {
          const int i = wm + mf*16 + g*4 + r;
          *(u16*)(T + d2*256 + ((i*2) ^ swz)) = f2b(acc[mf][nf][r]);
        }
      }
    }
    __builtin_amdgcn_s_barrier();
    const int b = bm >> 3, h = bn - 8;
#pragma unroll
    for (int it = 0; it < 8; it++) {
      const int L = it*4096 + tid*16;
      const int d2 = L >> 8, kk = L & 255;
      const int swz = (d2 & 7) << 4;
      bf16x8 vv = *(const bf16x8*)(T + d2*256 + (kk ^ swz));
      char* dst = (char*)Vt + ((size_t)((b*4 + h)*128 + d2) * 1024 + (size_t)(bm & 7)*128) * 2 + kk;
      *(bf16x8*)dst = vv;
    }
  } else {
#pragma unroll
    for (int mf = 0; mf < 4; mf++) {
#pragma unroll
      for (int nf = 0; nf < 4; nf++) {
        const int n = bn*128 + wn + nf*16 + c;
#pragma unroll
        for (int r = 0; r < 4; r++) {
          const int m = bm*128 + wm + mf*16 + g*4 + r;   // = b*1024 + i
          const int b = m >> 10, i = m & 1023;
          const float v = acc[mf][nf][r];
          if (n < 512) {
            int h = n >> 7, d = n & 127;
            Qb[(size_t)((b*4 + h)*1024 + i)*128 + d] = f2b(v);
          } else if (n < 1024) {
            int h = (n - 512) >> 7, d = n & 127;
            Kb[(size_t)((b*4 + h)*1024 + i)*128 + d] = f2b(v);
          } else if (n >= 1536 && n < 1788) {
            int q = n - 1536, h = q / 63, r2 = q - h*63;
            RELW[(size_t)((b*4 + h)*1024 + i)*64 + r2] = v;
          } else if (n >= 1788 && n < 2040) {
            int q = n - 1788, h = q / 63, r2 = q - h*63;
            RELH[(size_t)((b*4 + h)*1024 + i)*64 + r2] = v;
          }
        }
      }
    }
  }
#undef G_STAGE
}

// ---------------- fused flash attention, SWAPPED QK^T (q lane-local softmax) ----------------
// grid (32 bh, 16 q-tiles), 256 threads (4 waves x 16 Q-rows). KV tiles of 64, 2-deep pipeline.
// S' = K Q^T: acc[fn][r] = S[kv = jt*64+fn*16+g*4+r][q = i0+w*16+c]  ->  kv-reduce is
// 15 in-reg ops + 2 shfl_xor; bias = 8 hoisted xw + 2 prefetched yh loads per jt;
// P packed via v_cvt_pk_bf16_f32 into 4 ds_write_b64 (same Pl layout PV already reads).
__global__ __launch_bounds__(256) void attn_fused(
    const u16* __restrict__ Qb, const u16* __restrict__ Kb, const u16* __restrict__ Vt,
    const float* __restrict__ RELW, const float* __restrict__ RELH,
    u16* __restrict__ AO)
{
  __shared__ char sm[73728];   // [p][Kt 16KB][Vts 16KB] x2, Pl 8KB
  char* const Pl = sm + 65536;
  const int tid = threadIdx.x;
  const int w = tid >> 6, l = tid & 63, g = l >> 4, c = l & 15;
  const int bh = blockIdx.x, qt = blockIdx.y;
  const int i0 = qt * 64;

  // Q fragments: lane holds Q row (i0+w*16+c), k-chunks; serves as B-frag of Q^T.
  bf16x8 qf[4];
  {
    const char* qbase = (const char*)Qb + (size_t)(bh*1024 + i0 + w*16 + c) * 256;
#pragma unroll
    for (int s = 0; s < 4; s++) qf[s] = *(const bf16x8*)(qbase + s*64 + g*16);
  }

  // per-lane q = i0 + w*16 + c; hoisted bias
  const int i = i0 + w*16 + c;
  const int xi = i & 31, yi = i >> 5;
  const float* rw = RELW + ((size_t)(bh*1024 + i) << 6);
  const float* rhb = RELH + ((size_t)(bh*1024 + i) << 6) + (31 - yi);
  float xwh[2][4];
#pragma unroll
  for (int e = 0; e < 2; e++)
#pragma unroll
    for (int r = 0; r < 4; r++) xwh[e][r] = rw[e*16 + g*4 + r - xi + 31];

  f32x4 Oacc[8];
#pragma unroll
  for (int fd = 0; fd < 8; fd++) Oacc[fd] = f32x4{0.f, 0.f, 0.f, 0.f};
  float m_q = -INFINITY, l_q = 0.f;

#define A_STAGE(jt, p)                                                                     \
  {                                                                                        \
    char* Kt_ = sm + (p)*32768;                                                            \
    char* Vs_ = Kt_ + 16384;                                                               \
    const int j0b = (jt) * 64;                                                             \
    _Pragma("unroll")                                                                      \
    for (int t = 0; t < 4; t++) {                                                          \
      const int L = (w*4 + t)*1024 + l*16;                                                 \
      const int jr = L >> 8, jb = L & 255;                                                 \
      glds16((const char*)Kb + (size_t)(bh*1024 + j0b + jr) * 256 + (jb ^ ((jr & 7) << 4)),\
             Kt_ + L);                                                                     \
      const int dr = L >> 7, db = L & 127;                                                 \
      glds16((const char*)Vt + (size_t)(bh*128 + dr) * 2048 + j0b*2 + (db ^ ((dr & 7) << 4)),\
             Vs_ + L);                                                                     \
    }                                                                                      \
  }

  A_STAGE(0, 0);
  A_STAGE(1, 1);
  float yh0 = rhb[0], yh1 = rhb[1];   // jt = 0 bias (retired before first stage wait matters)

#pragma unroll 2
  for (int jt = 0; jt < 16; jt++) {
    const int p = jt & 1;
    if (jt < 15) { asm volatile("s_waitcnt vmcnt(8)" ::: "memory"); }
    else         { asm volatile("s_waitcnt vmcnt(0)" ::: "memory"); }
    __builtin_amdgcn_s_barrier();

    const char* Kt_ = sm + p*32768;
    const char* Vs_ = Kt_ + 16384;

    // S' = K Q^T  (kf = A-frag rows kv=fn*16+c, qf = B-frag cols q=c)
    f32x4 acc[4];
#pragma unroll
    for (int fn = 0; fn < 4; fn++) acc[fn] = f32x4{0.f, 0.f, 0.f, 0.f};
    __builtin_amdgcn_s_setprio(1);
#pragma unroll
    for (int s = 0; s < 4; s++) {
      const int koff = (s*64 + g*16) ^ ((c & 7) << 4);
#pragma unroll
      for (int fn = 0; fn < 4; fn++) {
        bf16x8 kf = *(const bf16x8*)(Kt_ + (fn*16 + c)*256 + koff);
        acc[fn] = __builtin_amdgcn_mfma_f32_16x16x32_bf16(kf, qf[s], acc[fn], 0, 0, 0);
      }
    }
    __builtin_amdgcn_s_setprio(0);

    // bias add: kv = jt*64 + fn*16 + g*4 + r -> xj = (fn&1)*16+g*4+r, yj = jt*2+(fn>>1)
#pragma unroll
    for (int fn = 0; fn < 4; fn++)
#pragma unroll
      for (int r = 0; r < 4; r++)
        acc[fn][r] += xwh[fn & 1][r] + ((fn >> 1) ? yh1 : yh0);

    // lane-local kv-reduce (q = c fixed per lane)
    float mx = fmaxf(fmaxf(fmaxf(acc[0][0], acc[0][1]), fmaxf(acc[0][2], acc[0][3])),
                     fmaxf(fmaxf(acc[1][0], acc[1][1]), fmaxf(acc[1][2], acc[1][3])));
    mx = fmaxf(mx, fmaxf(fmaxf(fmaxf(acc[2][0], acc[2][1]), fmaxf(acc[2][2], acc[2][3])),
                         fmaxf(fmaxf(acc[3][0], acc[3][1]), fmaxf(acc[3][2], acc[3][3]))));
    mx = fmaxf(mx, __shfl_xor(mx, 16));
    mx = fmaxf(mx, __shfl_xor(mx, 32));
    const float mnew = fmaxf(m_q, mx);
    const float scq = __expf(m_q - mnew);
    m_q = mnew;

    float pv[4][4];
    float ps = 0.f;
#pragma unroll
    for (int fn = 0; fn < 4; fn++) {
#pragma unroll
      for (int r = 0; r < 4; r++) {
        pv[fn][r] = __expf(acc[fn][r] - mnew);
        ps += pv[fn][r];
      }
    }
    ps += __shfl_xor(ps, 16);
    ps += __shfl_xor(ps, 32);
    l_q = l_q * scq + ps;

    // prefetch next jt's yh BEFORE the next stage issue (keeps vmcnt counting clean)
    float nyh0 = 0.f, nyh1 = 0.f;
    if (jt < 15) { nyh0 = rhb[(jt + 1)*2]; nyh1 = rhb[(jt + 1)*2 + 1]; }

    // P pack -> Pl[q=c][kv] (same layout PV reads), 4x ds_write_b64, 2-way-free banks
    {
      char* pb = Pl + w*2048 + c*128;
      const int swz = (c & 7) << 4;
#pragma unroll
      for (int fn = 0; fn < 4; fn++) {
        u32 w0, w1;
        asm("v_cvt_pk_bf16_f32 %0, %1, %2" : "=v"(w0) : "v"(pv[fn][0]), "v"(pv[fn][1]));
        asm("v_cvt_pk_bf16_f32 %0, %1, %2" : "=v"(w1) : "v"(pv[fn][2]), "v"(pv[fn][3]));
        uint2 pk; pk.x = w0; pk.y = w1;
        *(uint2*)(pb + ((fn*32 + g*8) ^ swz)) = pk;
      }
    }

    // redistribute sc to row space (Oacc rows q = g*4+r), rescale O
#pragma unroll
    for (int r = 0; r < 4; r++) {
      const float scr = __shfl(scq, g*4 + r, 16);
#pragma unroll
      for (int fd = 0; fd < 8; fd++) Oacc[fd][r] *= scr;
    }

    // O += P V
    __builtin_amdgcn_s_setprio(1);
#pragma unroll
    for (int s = 0; s < 2; s++) {
      const int koff = (s*64 + g*16) ^ ((c & 7) << 4);
      bf16x8 pf = *(const bf16x8*)(Pl + w*2048 + c*128 + koff);
#pragma unroll
      for (int fd = 0; fd < 8; fd++) {
        bf16x8 vf = *(const bf16x8*)(Vs_ + (fd*16 + c)*128 + koff);
        Oacc[fd] = __builtin_amdgcn_mfma_f32_16x16x32_bf16(pf, vf, Oacc[fd], 0, 0, 0);
      }
    }
    __builtin_amdgcn_s_setprio(0);

    __builtin_amdgcn_s_barrier();
    if (jt < 14) A_STAGE(jt + 2, p);
    yh0 = nyh0; yh1 = nyh1;
  }

  // epilogue: pull l into row space once, store
  const int b = bh >> 2, h = bh & 3;
#pragma unroll
  for (int r = 0; r < 4; r++) {
    const float lr = __shfl(l_q, g*4 + r, 16);
    const float linv = 1.0f / lr;
    const int io = i0 + w*16 + g*4 + r;
#pragma unroll
    for (int fd = 0; fd < 8; fd++) {
      AO[(size_t)(b*1024 + io)*512 + h*128 + fd*16 + c] = f2b(Oacc[fd][r] * linv);
    }
  }
#undef A_STAGE
}

// ---------------- launcher ----------------
extern "C" void kernel_launch(void* const* d_in, const int* in_sizes, int n_in,
                              void* d_out, int out_size, void* d_ws, size_t ws_size,
                              hipStream_t stream) {
  const float* x   = (const float*)d_in[0];
  const float* Wq  = (const float*)d_in[1];
  const float* Wk  = (const float*)d_in[2];
  const float* Wv  = (const float*)d_in[3];
  const float* Wo  = (const float*)d_in[4];
  const float* pew = (const float*)d_in[5];
  const float* peh = (const float*)d_in[6];

  char* ws = (char*)d_ws;
  u16* xb    = (u16*)ws;    ws += (size_t)8192*512*2;
  u16* WbigT = (u16*)ws;    ws += (size_t)2048*512*2;
  u16* WoT   = (u16*)ws;    ws += (size_t)512*512*2;
  u16* Qb    = (u16*)ws;    ws += (size_t)32*1024*128*2;
  u16* Kb    = (u16*)ws;    ws += (size_t)32*1024*128*2;
  u16* Vt    = (u16*)ws;    ws += (size_t)32*1024*128*2;
  float* RELW = (float*)ws; ws += (size_t)32*1024*64*4;
  float* RELH = (float*)ws; ws += (size_t)32*1024*64*4;
  u16* AO    = (u16*)ws;    ws += (size_t)8192*512*2;

  castx<<<4096, 256, 0, stream>>>(x, xb);
  buildw<<<2056, 256, 0, stream>>>(Wq, Wk, Wv, Wo, WbigT, WoT);
  wpe_kernel<<<512, 256, 0, stream>>>(Wq, pew, peh, WbigT);
  gemm_bt<1><<<dim3(64, 16), 256, 0, stream>>>(xb, WbigT, nullptr, Qb, Kb, Vt, RELW, RELH);
  attn_fused<<<dim3(32, 16), 256, 0, stream>>>(Qb, Kb, Vt, RELW, RELH, AO);
  gemm_bt<0><<<dim3(64, 4), 256, 0, stream>>>(AO, WoT, (float*)d_out,
                                              nullptr, nullptr, nullptr, nullptr, nullptr);
}

// Round 5
// 97.635 us; speedup vs baseline: 1.3131x; 1.0708x over previous
//
#include <hip/hip_runtime.h>
#include <math.h>

typedef unsigned short u16;
typedef unsigned int u32;
typedef __bf16 bf16x8 __attribute__((ext_vector_type(8)));
typedef float f32x4 __attribute__((ext_vector_type(4)));

__device__ __forceinline__ u16 f2b(float f) {
  u32 u = __builtin_bit_cast(u32, f);
  u32 r = (u + 0x7FFFu + ((u >> 16) & 1u)) >> 16;
  return (u16)r;
}

__device__ __forceinline__ void glds16(const void* g, void* lds) {
  __builtin_amdgcn_global_load_lds(
      (const __attribute__((address_space(1))) void*)(void*)(const_cast<void*>(g)),
      (__attribute__((address_space(3))) void*)lds, 16, 0, 0);
}

// ---------------- prep kernels ----------------

__global__ __launch_bounds__(256) void castx(const float* __restrict__ x, u16* __restrict__ xb) {
  int idx = blockIdx.x * 256 + threadIdx.x;
  float4 v = ((const float4*)x)[idx];
  ushort4 o;
  o.x = f2b(v.x); o.y = f2b(v.y); o.z = f2b(v.z); o.w = f2b(v.w);
  ((ushort4*)xb)[idx] = o;
}

__global__ __launch_bounds__(256) void buildw(const float* __restrict__ Wq, const float* __restrict__ Wk,
                                              const float* __restrict__ Wv, const float* __restrict__ Wo,
                                              u16* __restrict__ WbigT, u16* __restrict__ WoT) {
  const float SCALE = 0.08838834764831845f;  // 1/sqrt(128)
  int row = blockIdx.x;  // 0..2055
  int t = threadIdx.x;
  if (row < 512) {
    for (int k = t; k < 512; k += 256) WbigT[row*512 + k] = f2b(Wq[k*512 + row] * SCALE);
  } else if (row < 1024) {
    int n = row - 512;
    for (int k = t; k < 512; k += 256) WbigT[row*512 + k] = f2b(Wk[k*512 + n]);
  } else if (row < 1536) {
    int n = row - 1024;
    for (int k = t; k < 512; k += 256) WbigT[row*512 + k] = f2b(Wv[k*512 + n]);
  } else if (row < 1544) {
    int rr = row - 1536 + 2040;
    for (int k = t; k < 512; k += 256) WbigT[rr*512 + k] = 0;
  } else {
    int n = row - 1544;
    for (int k = t; k < 512; k += 256) WoT[n*512 + k] = f2b(Wo[k*512 + n]);
  }
}

__global__ __launch_bounds__(256) void wpe_kernel(const float* __restrict__ Wq, const float* __restrict__ pew,
                                                  const float* __restrict__ peh, u16* __restrict__ WbigT) {
  int k = blockIdx.x;  // 0..511
  int t = threadIdx.x;
  __shared__ float wrow[512];
  for (int j = t; j < 512; j += 256) wrow[j] = Wq[k*512 + j];
  __syncthreads();
  if (t < 252) {
    int h = t / 63, r = t - h*63;
    float aw = 0.f, ah = 0.f;
    for (int d = 0; d < 128; d++) {
      float qv = wrow[h*128 + d];
      aw += qv * pew[d*63 + r];
      ah += qv * peh[d*63 + r];
    }
    const float SCALE = 0.08838834764831845f;
    WbigT[(size_t)(1536 + t)*512 + k] = f2b(aw * SCALE);
    WbigT[(size_t)(1788 + t)*512 + k] = f2b(ah * SCALE);
  }
}

// ---------------- fused QKV+REL GEMM: 256x256 tile, 8 waves (2Mx4N), BK=64 ----------------
// A [8192][512] bf16, Bt [2048][512] bf16. Grid (32,8) = 256 blocks = 1/CU.
// Same 2-deep pipeline discipline as before (8 glds16/thread/stage, vmcnt(8)).
// Epilogues: Q/K via LDS m-major transpose -> coalesced 16B stores; V via n-major
// transpose -> coalesced V^T stores; REL direct fp32.
__global__ __launch_bounds__(512) void gemm256(
    const u16* __restrict__ A, const u16* __restrict__ Bt,
    u16* __restrict__ Qb, u16* __restrict__ Kb, u16* __restrict__ Vt,
    float* __restrict__ RELW, float* __restrict__ RELH)
{
  __shared__ char sm[131072];   // buf p at p*65536: A 32KB + B 32KB
  const int tid = threadIdx.x;
  const int w = tid >> 6, l = tid & 63, g = l >> 4, c = l & 15;
  const int bm = blockIdx.x, bn = blockIdx.y;
  const int wm = w >> 2, wn = w & 3;   // 2 x 4 waves

  f32x4 acc[8][4];
#pragma unroll
  for (int i = 0; i < 8; i++)
#pragma unroll
    for (int j = 0; j < 4; j++) acc[i][j] = f32x4{0.f, 0.f, 0.f, 0.f};

  const char* Ab = (const char*)A;
  const char* Bb = (const char*)Bt;
  const int rsub = l >> 3;
  const int csw = (((l & 7) ^ rsub) << 4);   // pre-swizzled source byte within 128B row-slice

#define G_STAGE(kb, p)                                                                    \
  {                                                                                       \
    char* As_ = sm + (p)*65536;                                                           \
    char* Bs_ = As_ + 32768;                                                              \
    const int kbyte = (kb) * 128;                                                         \
    _Pragma("unroll")                                                                     \
    for (int i2 = 0; i2 < 4; i2++) {                                                      \
      const int row = i2*64 + w*8 + rsub;                                                 \
      glds16(Ab + (size_t)(bm*256 + row) * 1024 + kbyte + csw, As_ + i2*8192 + w*1024);   \
      glds16(Bb + (size_t)(bn*256 + row) * 1024 + kbyte + csw, Bs_ + i2*8192 + w*1024);   \
    }                                                                                     \
  }

  G_STAGE(0, 0);
  G_STAGE(1, 1);

#pragma unroll
  for (int kb = 0; kb < 8; kb++) {
    const int p = kb & 1;
    if (kb < 7) { asm volatile("s_waitcnt vmcnt(8)" ::: "memory"); }
    else        { asm volatile("s_waitcnt vmcnt(0)" ::: "memory"); }
    __builtin_amdgcn_s_barrier();
    const char* As_ = sm + p*65536;
    const char* Bs_ = As_ + 32768;
#pragma unroll
    for (int ks = 0; ks < 2; ks++) {
      const int koff = (ks*64 + g*16) ^ ((c & 7) << 4);
      bf16x8 af[8], bfr[4];
#pragma unroll
      for (int mf = 0; mf < 8; mf++)
        af[mf] = *(const bf16x8*)(As_ + (wm*128 + mf*16 + c)*128 + koff);
#pragma unroll
      for (int nf = 0; nf < 4; nf++)
        bfr[nf] = *(const bf16x8*)(Bs_ + (wn*64 + nf*16 + c)*128 + koff);
#pragma unroll
      for (int mf = 0; mf < 8; mf++)
#pragma unroll
        for (int nf = 0; nf < 4; nf++)
          acc[mf][nf] = __builtin_amdgcn_mfma_f32_16x16x32_bf16(af[mf], bfr[nf], acc[mf][nf], 0, 0, 0);
    }
    __builtin_amdgcn_s_barrier();
    if (kb < 6) G_STAGE(kb + 2, p);
  }
#undef G_STAGE

  const int b = bm >> 2;
  const int iBase = (bm & 3) * 256;

  if (bn < 4) {
    // Q (bn 0-1) / K (bn 2-3): LDS m-major [lm][ln] bf16, then coalesced 16B stores
    u16* dst0 = (bn < 2) ? Qb : Kb;
    const int bnn = bn & 1;
#pragma unroll
    for (int mf = 0; mf < 8; mf++) {
      const int lmb = wm*128 + mf*16 + g*4;
#pragma unroll
      for (int nf = 0; nf < 4; nf++) {
        const int ln = wn*64 + nf*16 + c;
#pragma unroll
        for (int r = 0; r < 4; r++) {
          const int lm = lmb + r;
          *(u16*)(sm + lm*512 + ((ln*2) ^ ((lm & 7) << 4))) = f2b(acc[mf][nf][r]);
        }
      }
    }
    __builtin_amdgcn_s_barrier();
#pragma unroll
    for (int it = 0; it < 16; it++) {
      const int gid = it*512 + tid;
      const int lm2 = gid >> 5, gsub = gid & 31;
      bf16x8 v = *(const bf16x8*)(sm + lm2*512 + ((gsub*16) ^ ((lm2 & 7) << 4)));
      const int h = bnn*2 + (gsub >> 4);
      const int d0 = (gsub & 15) * 8;
      *(bf16x8*)(dst0 + ((size_t)(b*4 + h)*1024 + iBase + lm2)*128 + d0) = v;
    }
  } else if (bn < 6) {
    // V: LDS n-major [ln][lm] bf16 (8B packed writes), then coalesced V^T stores
#pragma unroll
    for (int mf = 0; mf < 8; mf++) {
      const int lmb = wm*128 + mf*16 + g*4;
#pragma unroll
      for (int nf = 0; nf < 4; nf++) {
        const int ln = wn*64 + nf*16 + c;
        u32 w0, w1;
        asm("v_cvt_pk_bf16_f32 %0, %1, %2" : "=v"(w0) : "v"(acc[mf][nf][0]), "v"(acc[mf][nf][1]));
        asm("v_cvt_pk_bf16_f32 %0, %1, %2" : "=v"(w1) : "v"(acc[mf][nf][2]), "v"(acc[mf][nf][3]));
        uint2 pk; pk.x = w0; pk.y = w1;
        *(uint2*)(sm + ln*512 + ((lmb*2) ^ ((c & 7) << 4))) = pk;
      }
    }
    __builtin_amdgcn_s_barrier();
#pragma unroll
    for (int it = 0; it < 16; it++) {
      const int gid = it*512 + tid;
      const int ln2 = gid >> 5, gsub = gid & 31;
      bf16x8 v = *(const bf16x8*)(sm + ln2*512 + ((gsub*16) ^ ((ln2 & 7) << 4)));
      const int q2 = (bn - 4)*256 + ln2;
      const int h = q2 >> 7, d = q2 & 127;
      *(bf16x8*)(Vt + ((size_t)(b*4 + h)*128 + d)*1024 + iBase + gsub*8) = v;
    }
  } else {
    // REL: n in [1536,2048): q<252 -> RELW, 252<=q<504 -> RELH, else zero cols (skip)
#pragma unroll
    for (int mf = 0; mf < 8; mf++) {
      const int lmb = wm*128 + mf*16 + g*4;
#pragma unroll
      for (int nf = 0; nf < 4; nf++) {
        const int q = (bn - 6)*256 + wn*64 + nf*16 + c;
        if (q < 252) {
          const int h = q / 63, r2 = q - h*63;
#pragma unroll
          for (int r = 0; r < 4; r++)
            RELW[(size_t)((b*4 + h)*1024 + iBase + lmb + r)*64 + r2] = acc[mf][nf][r];
        } else if (q < 504) {
          const int qq = q - 252;
          const int h = qq / 63, r2 = qq - h*63;
#pragma unroll
          for (int r = 0; r < 4; r++)
            RELH[(size_t)((b*4 + h)*1024 + iBase + lmb + r)*64 + r2] = acc[mf][nf][r];
        }
      }
    }
  }
}

// ---------------- output GEMM (128x128 tile, 4 waves, 2-deep pipeline) ----------------
__global__ __launch_bounds__(256) void gemm_out(
    const u16* __restrict__ A, const u16* __restrict__ Bt, float* __restrict__ outF)
{
  __shared__ char sm[65536];
  const int tid = threadIdx.x;
  const int w = tid >> 6, l = tid & 63, g = l >> 4, c = l & 15;
  const int bm = blockIdx.x, bn = blockIdx.y;
  const int wm = (w >> 1) * 64, wn = (w & 1) * 64;

  f32x4 acc[4][4];
#pragma unroll
  for (int i = 0; i < 4; i++)
#pragma unroll
    for (int j = 0; j < 4; j++) acc[i][j] = f32x4{0.f, 0.f, 0.f, 0.f};

  const char* Ab = (const char*)A;
  const char* Bb = (const char*)Bt;
  const int rsub = l >> 3;
  const int csw = (((l & 7) ^ rsub) << 4);

#define G_STAGE(kb, p)                                                                    \
  {                                                                                       \
    char* As_ = sm + (p)*32768;                                                           \
    char* Bs_ = As_ + 16384;                                                              \
    const int kbyte = (kb) * 128;                                                         \
    _Pragma("unroll")                                                                     \
    for (int t = 0; t < 4; t++) {                                                         \
      const int row = (w*4 + t)*8 + rsub;                                                 \
      glds16(Ab + (size_t)(bm*128 + row) * 1024 + kbyte + csw, As_ + (w*4 + t)*1024);     \
      glds16(Bb + (size_t)(bn*128 + row) * 1024 + kbyte + csw, Bs_ + (w*4 + t)*1024);     \
    }                                                                                     \
  }

  G_STAGE(0, 0);
  G_STAGE(1, 1);

#pragma unroll
  for (int kb = 0; kb < 8; kb++) {
    const int p = kb & 1;
    if (kb < 7) { asm volatile("s_waitcnt vmcnt(8)" ::: "memory"); }
    else        { asm volatile("s_waitcnt vmcnt(0)" ::: "memory"); }
    __builtin_amdgcn_s_barrier();
    const char* As_ = sm + p*32768;
    const char* Bs_ = As_ + 16384;
#pragma unroll
    for (int ks = 0; ks < 2; ks++) {
      const int koff = (ks*64 + g*16) ^ ((c & 7) << 4);
      bf16x8 af[4], bfr[4];
#pragma unroll
      for (int mf = 0; mf < 4; mf++)
        af[mf] = *(const bf16x8*)(As_ + (wm + mf*16 + c)*128 + koff);
#pragma unroll
      for (int nf = 0; nf < 4; nf++)
        bfr[nf] = *(const bf16x8*)(Bs_ + (wn + nf*16 + c)*128 + koff);
#pragma unroll
      for (int mf = 0; mf < 4; mf++)
#pragma unroll
        for (int nf = 0; nf < 4; nf++)
          acc[mf][nf] = __builtin_amdgcn_mfma_f32_16x16x32_bf16(af[mf], bfr[nf], acc[mf][nf], 0, 0, 0);
    }
    __builtin_amdgcn_s_barrier();
    if (kb < 6) G_STAGE(kb + 2, p);
  }
#undef G_STAGE

#pragma unroll
  for (int mf = 0; mf < 4; mf++) {
#pragma unroll
    for (int nf = 0; nf < 4; nf++) {
      const int n = bn*128 + wn + nf*16 + c;
#pragma unroll
      for (int r = 0; r < 4; r++) {
        const int m = bm*128 + wm + mf*16 + g*4 + r;
        outF[(size_t)m*512 + n] = acc[mf][nf][r];
      }
    }
  }
}

// ---------------- fused flash attention, SWAPPED QK^T (q lane-local softmax) ----------------
__global__ __launch_bounds__(256) void attn_fused(
    const u16* __restrict__ Qb, const u16* __restrict__ Kb, const u16* __restrict__ Vt,
    const float* __restrict__ RELW, const float* __restrict__ RELH,
    u16* __restrict__ AO)
{
  __shared__ char sm[73728];   // [p][Kt 16KB][Vts 16KB] x2, Pl 8KB
  char* const Pl = sm + 65536;
  const int tid = threadIdx.x;
  const int w = tid >> 6, l = tid & 63, g = l >> 4, c = l & 15;
  const int bh = blockIdx.x, qt = blockIdx.y;
  const int i0 = qt * 64;

  bf16x8 qf[4];
  {
    const char* qbase = (const char*)Qb + (size_t)(bh*1024 + i0 + w*16 + c) * 256;
#pragma unroll
    for (int s = 0; s < 4; s++) qf[s] = *(const bf16x8*)(qbase + s*64 + g*16);
  }

  const int i = i0 + w*16 + c;
  const int xi = i & 31, yi = i >> 5;
  const float* rw = RELW + ((size_t)(bh*1024 + i) << 6);
  const float* rhb = RELH + ((size_t)(bh*1024 + i) << 6) + (31 - yi);
  float xwh[2][4];
#pragma unroll
  for (int e = 0; e < 2; e++)
#pragma unroll
    for (int r = 0; r < 4; r++) xwh[e][r] = rw[e*16 + g*4 + r - xi + 31];

  f32x4 Oacc[8];
#pragma unroll
  for (int fd = 0; fd < 8; fd++) Oacc[fd] = f32x4{0.f, 0.f, 0.f, 0.f};
  float m_q = -INFINITY, l_q = 0.f;

#define A_STAGE(jt, p)                                                                     \
  {                                                                                        \
    char* Kt_ = sm + (p)*32768;                                                            \
    char* Vs_ = Kt_ + 16384;                                                               \
    const int j0b = (jt) * 64;                                                             \
    _Pragma("unroll")                                                                      \
    for (int t = 0; t < 4; t++) {                                                          \
      const int L = (w*4 + t)*1024 + l*16;                                                 \
      const int jr = L >> 8, jb = L & 255;                                                 \
      glds16((const char*)Kb + (size_t)(bh*1024 + j0b + jr) * 256 + (jb ^ ((jr & 7) << 4)),\
             Kt_ + L);                                                                     \
      const int dr = L >> 7, db = L & 127;                                                 \
      glds16((const char*)Vt + (size_t)(bh*128 + dr) * 2048 + j0b*2 + (db ^ ((dr & 7) << 4)),\
             Vs_ + L);                                                                     \
    }                                                                                      \
  }

  A_STAGE(0, 0);
  A_STAGE(1, 1);
  float yh0 = rhb[0], yh1 = rhb[1];

#pragma unroll 2
  for (int jt = 0; jt < 16; jt++) {
    const int p = jt & 1;
    if (jt < 15) { asm volatile("s_waitcnt vmcnt(8)" ::: "memory"); }
    else         { asm volatile("s_waitcnt vmcnt(0)" ::: "memory"); }
    __builtin_amdgcn_s_barrier();

    const char* Kt_ = sm + p*32768;
    const char* Vs_ = Kt_ + 16384;

    f32x4 acc[4];
#pragma unroll
    for (int fn = 0; fn < 4; fn++) acc[fn] = f32x4{0.f, 0.f, 0.f, 0.f};
    __builtin_amdgcn_s_setprio(1);
#pragma unroll
    for (int s = 0; s < 4; s++) {
      const int koff = (s*64 + g*16) ^ ((c & 7) << 4);
#pragma unroll
      for (int fn = 0; fn < 4; fn++) {
        bf16x8 kf = *(const bf16x8*)(Kt_ + (fn*16 + c)*256 + koff);
        acc[fn] = __builtin_amdgcn_mfma_f32_16x16x32_bf16(kf, qf[s], acc[fn], 0, 0, 0);
      }
    }
    __builtin_amdgcn_s_setprio(0);

#pragma unroll
    for (int fn = 0; fn < 4; fn++)
#pragma unroll
      for (int r = 0; r < 4; r++)
        acc[fn][r] += xwh[fn & 1][r] + ((fn >> 1) ? yh1 : yh0);

    float mx = fmaxf(fmaxf(fmaxf(acc[0][0], acc[0][1]), fmaxf(acc[0][2], acc[0][3])),
                     fmaxf(fmaxf(acc[1][0], acc[1][1]), fmaxf(acc[1][2], acc[1][3])));
    mx = fmaxf(mx, fmaxf(fmaxf(fmaxf(acc[2][0], acc[2][1]), fmaxf(acc[2][2], acc[2][3])),
                         fmaxf(fmaxf(acc[3][0], acc[3][1]), fmaxf(acc[3][2], acc[3][3]))));
    mx = fmaxf(mx, __shfl_xor(mx, 16));
    mx = fmaxf(mx, __shfl_xor(mx, 32));
    const float mnew = fmaxf(m_q, mx);
    const float scq = __expf(m_q - mnew);
    m_q = mnew;

    float pv[4][4];
    float ps = 0.f;
#pragma unroll
    for (int fn = 0; fn < 4; fn++) {
#pragma unroll
      for (int r = 0; r < 4; r++) {
        pv[fn][r] = __expf(acc[fn][r] - mnew);
        ps += pv[fn][r];
      }
    }
    ps += __shfl_xor(ps, 16);
    ps += __shfl_xor(ps, 32);
    l_q = l_q * scq + ps;

    float nyh0 = 0.f, nyh1 = 0.f;
    if (jt < 15) { nyh0 = rhb[(jt + 1)*2]; nyh1 = rhb[(jt + 1)*2 + 1]; }

    {
      char* pb = Pl + w*2048 + c*128;
      const int swz = (c & 7) << 4;
#pragma unroll
      for (int fn = 0; fn < 4; fn++) {
        u32 w0, w1;
        asm("v_cvt_pk_bf16_f32 %0, %1, %2" : "=v"(w0) : "v"(pv[fn][0]), "v"(pv[fn][1]));
        asm("v_cvt_pk_bf16_f32 %0, %1, %2" : "=v"(w1) : "v"(pv[fn][2]), "v"(pv[fn][3]));
        uint2 pk; pk.x = w0; pk.y = w1;
        *(uint2*)(pb + ((fn*32 + g*8) ^ swz)) = pk;
      }
    }

#pragma unroll
    for (int r = 0; r < 4; r++) {
      const float scr = __shfl(scq, g*4 + r, 16);
#pragma unroll
      for (int fd = 0; fd < 8; fd++) Oacc[fd][r] *= scr;
    }

    __builtin_amdgcn_s_setprio(1);
#pragma unroll
    for (int s = 0; s < 2; s++) {
      const int koff = (s*64 + g*16) ^ ((c & 7) << 4);
      bf16x8 pf = *(const bf16x8*)(Pl + w*2048 + c*128 + koff);
#pragma unroll
      for (int fd = 0; fd < 8; fd++) {
        bf16x8 vf = *(const bf16x8*)(Vs_ + (fd*16 + c)*128 + koff);
        Oacc[fd] = __builtin_amdgcn_mfma_f32_16x16x32_bf16(pf, vf, Oacc[fd], 0, 0, 0);
      }
    }
    __builtin_amdgcn_s_setprio(0);

    __builtin_amdgcn_s_barrier();
    if (jt < 14) A_STAGE(jt + 2, p);
    yh0 = nyh0; yh1 = nyh1;
  }

  const int b = bh >> 2, h = bh & 3;
#pragma unroll
  for (int r = 0; r < 4; r++) {
    const float lr = __shfl(l_q, g*4 + r, 16);
    const float linv = 1.0f / lr;
    const int io = i0 + w*16 + g*4 + r;
#pragma unroll
    for (int fd = 0; fd < 8; fd++) {
      AO[(size_t)(b*1024 + io)*512 + h*128 + fd*16 + c] = f2b(Oacc[fd][r] * linv);
    }
  }
#undef A_STAGE
}

// ---------------- launcher ----------------
extern "C" void kernel_launch(void* const* d_in, const int* in_sizes, int n_in,
                              void* d_out, int out_size, void* d_ws, size_t ws_size,
                              hipStream_t stream) {
  const float* x   = (const float*)d_in[0];
  const float* Wq  = (const float*)d_in[1];
  const float* Wk  = (const float*)d_in[2];
  const float* Wv  = (const float*)d_in[3];
  const float* Wo  = (const float*)d_in[4];
  const float* pew = (const float*)d_in[5];
  const float* peh = (const float*)d_in[6];

  char* ws = (char*)d_ws;
  u16* xb    = (u16*)ws;    ws += (size_t)8192*512*2;
  u16* WbigT = (u16*)ws;    ws += (size_t)2048*512*2;
  u16* WoT   = (u16*)ws;    ws += (size_t)512*512*2;
  u16* Qb    = (u16*)ws;    ws += (size_t)32*1024*128*2;
  u16* Kb    = (u16*)ws;    ws += (size_t)32*1024*128*2;
  u16* Vt    = (u16*)ws;    ws += (size_t)32*1024*128*2;
  float* RELW = (float*)ws; ws += (size_t)32*1024*64*4;
  float* RELH = (float*)ws; ws += (size_t)32*1024*64*4;
  u16* AO    = (u16*)ws;    ws += (size_t)8192*512*2;

  castx<<<4096, 256, 0, stream>>>(x, xb);
  buildw<<<2056, 256, 0, stream>>>(Wq, Wk, Wv, Wo, WbigT, WoT);
  wpe_kernel<<<512, 256, 0, stream>>>(Wq, pew, peh, WbigT);
  gemm256<<<dim3(32, 8), 512, 0, stream>>>(xb, WbigT, Qb, Kb, Vt, RELW, RELH);
  attn_fused<<<dim3(32, 16), 256, 0, stream>>>(Qb, Kb, Vt, RELW, RELH, AO);
  gemm_out<<<dim3(64, 4), 256, 0, stream>>>(AO, WoT, (float*)d_out);
}